// Round 1
// baseline (2493.963 us; speedup 1.0000x reference)
//
#include <hip/hip_runtime.h>
#include <hip/hip_bf16.h>
#include <math.h>

#define N_NODES 20000
#define N_EDGES 320000
#define N_GRAPHS 64
#define D_IN 771
#define HDIM 256
#define L_LAYERS 5

// ---------------- GEMM: C = op(A@B [+ bias]), A [M,K] rm, B [K,N] rm -------
// 64x64 block tile, BK=16, 256 threads, 4x4 thread tile.
template<int EPI> // 0: none, 1: bias+relu
__global__ __launch_bounds__(256)
void gemm_rm(const float* __restrict__ A, const float* __restrict__ B,
             const float* __restrict__ bias, float* __restrict__ C,
             int M, int N, int K) {
    __shared__ float As[16][68];
    __shared__ float Bs[16][68];
    const int tid = threadIdx.x;
    const int row0 = blockIdx.x * 64, col0 = blockIdx.y * 64;
    const int tm = (tid & 15) * 4, tn = (tid >> 4) * 4;
    const int ar = tid >> 2, ac = (tid & 3) * 4;
    const int br = tid >> 4, bc = (tid & 15) * 4;
    float acc[4][4] = {};
    const bool a_vec = ((K & 3) == 0);   // float4-alignable rows
    for (int k0 = 0; k0 < K; k0 += 16) {
        float a0 = 0.f, a1 = 0.f, a2 = 0.f, a3 = 0.f;
        const int arow = row0 + ar;
        if (arow < M) {
            const float* ap = A + (size_t)arow * K + k0 + ac;
            if (a_vec) {
                float4 v = *(const float4*)ap;
                a0 = v.x; a1 = v.y; a2 = v.z; a3 = v.w;
            } else {
                int rem = K - k0 - ac;
                if (rem > 0) a0 = ap[0];
                if (rem > 1) a1 = ap[1];
                if (rem > 2) a2 = ap[2];
                if (rem > 3) a3 = ap[3];
            }
        }
        As[ac + 0][ar] = a0; As[ac + 1][ar] = a1;
        As[ac + 2][ar] = a2; As[ac + 3][ar] = a3;
        float4 bv = {0.f, 0.f, 0.f, 0.f};
        if (k0 + br < K) bv = *(const float4*)(B + (size_t)(k0 + br) * N + col0 + bc);
        *(float4*)&Bs[br][bc] = bv;
        __syncthreads();
        #pragma unroll
        for (int kk = 0; kk < 16; kk++) {
            float4 av = *(const float4*)&As[kk][tm];
            float4 bw = *(const float4*)&Bs[kk][tn];
            float aa[4] = {av.x, av.y, av.z, av.w};
            float bb[4] = {bw.x, bw.y, bw.z, bw.w};
            #pragma unroll
            for (int i = 0; i < 4; i++)
                #pragma unroll
                for (int j = 0; j < 4; j++) acc[i][j] += aa[i] * bb[j];
        }
        __syncthreads();
    }
    #pragma unroll
    for (int i = 0; i < 4; i++) {
        int row = row0 + tm + i;
        if (row >= M) continue;
        float4 o;
        float* op = &o.x;
        #pragma unroll
        for (int j = 0; j < 4; j++) {
            float v = acc[i][j];
            if (EPI == 1) { v += bias[col0 + tn + j]; v = fmaxf(v, 0.f); }
            op[j] = v;
        }
        *(float4*)(C + (size_t)row * N + col0 + tn) = o;
    }
}

// ------------- fused GRU: gi = agg@WihT, gh = h@WhhT, gates, h_new ----------
// Block computes a 64-row x 64-col tile of h_new; needs 3 col-slabs of gi/gh.
__global__ __launch_bounds__(256)
void gru_fused(const float* __restrict__ agg, const float* __restrict__ hold,
               const float* __restrict__ wihT, const float* __restrict__ whhT,
               const float* __restrict__ bih, const float* __restrict__ bhh,
               float* __restrict__ hnew, int M) {
    __shared__ float Ai[16][68];
    __shared__ float Ah[16][68];
    __shared__ float Bi[3][16][68];
    __shared__ float Bh[3][16][68];
    const int tid = threadIdx.x;
    const int row0 = blockIdx.x * 64, col0 = blockIdx.y * 64;
    const int tm = (tid & 15) * 4, tn = (tid >> 4) * 4;
    const int ar = tid >> 2, ac = (tid & 3) * 4;
    const int br = tid >> 4, bc = (tid & 15) * 4;
    float gi[3][4][4] = {};
    float gh[3][4][4] = {};
    for (int k0 = 0; k0 < HDIM; k0 += 16) {
        const int arow = row0 + ar;
        float4 av = {0.f,0.f,0.f,0.f}, hv = {0.f,0.f,0.f,0.f};
        if (arow < M) {
            av = *(const float4*)(agg  + (size_t)arow * HDIM + k0 + ac);
            hv = *(const float4*)(hold + (size_t)arow * HDIM + k0 + ac);
        }
        Ai[ac + 0][ar] = av.x; Ai[ac + 1][ar] = av.y;
        Ai[ac + 2][ar] = av.z; Ai[ac + 3][ar] = av.w;
        Ah[ac + 0][ar] = hv.x; Ah[ac + 1][ar] = hv.y;
        Ah[ac + 2][ar] = hv.z; Ah[ac + 3][ar] = hv.w;
        #pragma unroll
        for (int s = 0; s < 3; s++) {
            *(float4*)&Bi[s][br][bc] =
                *(const float4*)(wihT + (size_t)(k0 + br) * (3*HDIM) + s*HDIM + col0 + bc);
            *(float4*)&Bh[s][br][bc] =
                *(const float4*)(whhT + (size_t)(k0 + br) * (3*HDIM) + s*HDIM + col0 + bc);
        }
        __syncthreads();
        #pragma unroll
        for (int kk = 0; kk < 16; kk++) {
            float4 a4 = *(const float4*)&Ai[kk][tm];
            float4 h4 = *(const float4*)&Ah[kk][tm];
            float aa[4] = {a4.x, a4.y, a4.z, a4.w};
            float hh[4] = {h4.x, h4.y, h4.z, h4.w};
            #pragma unroll
            for (int s = 0; s < 3; s++) {
                float4 b4 = *(const float4*)&Bi[s][kk][tn];
                float4 c4 = *(const float4*)&Bh[s][kk][tn];
                float bb[4] = {b4.x, b4.y, b4.z, b4.w};
                float cc[4] = {c4.x, c4.y, c4.z, c4.w};
                #pragma unroll
                for (int i = 0; i < 4; i++)
                    #pragma unroll
                    for (int j = 0; j < 4; j++) {
                        gi[s][i][j] += aa[i] * bb[j];
                        gh[s][i][j] += hh[i] * cc[j];
                    }
            }
        }
        __syncthreads();
    }
    #pragma unroll
    for (int i = 0; i < 4; i++) {
        int row = row0 + tm + i;
        if (row >= M) continue;
        float4 hv = *(const float4*)(hold + (size_t)row * HDIM + col0 + tn);
        float ho[4] = {hv.x, hv.y, hv.z, hv.w};
        float4 o;
        float* op = &o.x;
        #pragma unroll
        for (int j = 0; j < 4; j++) {
            int c = col0 + tn + j;
            float xr = gi[0][i][j] + bih[c]          + gh[0][i][j] + bhh[c];
            float xz = gi[1][i][j] + bih[HDIM + c]   + gh[1][i][j] + bhh[HDIM + c];
            float nn = gi[2][i][j] + bih[2*HDIM + c];
            float hn = gh[2][i][j] + bhh[2*HDIM + c];
            float r  = 1.f / (1.f + expf(-xr));
            float z  = 1.f / (1.f + expf(-xz));
            float n_ = tanhf(nn + r * hn);
            op[j] = (1.f - z) * n_ + z * ho[j];
        }
        *(float4*)(hnew + (size_t)row * HDIM + col0 + tn) = o;
    }
}

// -------------------------- CSR build ---------------------------------------
__global__ void transpose_gru(const float* __restrict__ wih, const float* __restrict__ whh,
                              float* __restrict__ wihT, float* __restrict__ whhT) {
    int idx = blockIdx.x * 256 + threadIdx.x;   // over 256*768, wT[k][n] = w[n][k]
    if (idx >= HDIM * 3 * HDIM) return;
    int k = idx / (3 * HDIM), n = idx % (3 * HDIM);
    wihT[idx] = wih[(size_t)n * HDIM + k];
    whhT[idx] = whh[(size_t)n * HDIM + k];
}

__global__ void edge_count(const int* __restrict__ ei, int* __restrict__ deg, int E) {
    int e = blockIdx.x * 256 + threadIdx.x;
    if (e < E) atomicAdd(&deg[ei[E + e]], 1);   // dst row
}

__global__ __launch_bounds__(1024)
void scan_rowptr(const int* __restrict__ deg, int* __restrict__ rowptr, int N) {
    __shared__ int bs[1024];
    const int tid = threadIdx.x;
    const int CH = (N + 1023) / 1024;
    const int base = tid * CH;
    int sum = 0;
    for (int i = 0; i < CH; i++) { int idx = base + i; sum += (idx < N) ? deg[idx] : 0; }
    bs[tid] = sum; __syncthreads();
    for (int off = 1; off < 1024; off <<= 1) {
        int v = (tid >= off) ? bs[tid - off] : 0;
        __syncthreads();
        bs[tid] += v;
        __syncthreads();
    }
    int run = (tid > 0) ? bs[tid - 1] : 0;
    for (int i = 0; i < CH; i++) {
        int idx = base + i;
        if (idx < N) { rowptr[idx] = run; run += deg[idx]; }
    }
    if (tid == 0) rowptr[N] = bs[1023];
}

__global__ void edge_bucket(const int* __restrict__ ei, int* __restrict__ cursor,
                            int* __restrict__ csrc, int E) {
    int e = blockIdx.x * 256 + threadIdx.x;
    if (e < E) {
        int d = ei[E + e];
        int p = atomicAdd(&cursor[d], 1);
        csrc[p] = ei[e];   // src
    }
}

// one wave per node: agg[v] = sum over in-edges of m[src]
__global__ __launch_bounds__(256)
void agg_csr(const float* __restrict__ m, const int* __restrict__ rowptr,
             const int* __restrict__ csrc, float* __restrict__ agg, int N) {
    int wave = (blockIdx.x * 256 + threadIdx.x) >> 6;
    int lane = threadIdx.x & 63;
    if (wave >= N) return;
    int s0 = rowptr[wave], s1 = rowptr[wave + 1];
    float4 acc = {0.f, 0.f, 0.f, 0.f};
    for (int e = s0; e < s1; e++) {
        int s = csrc[e];
        float4 v = *(const float4*)(m + (size_t)s * HDIM + lane * 4);
        acc.x += v.x; acc.y += v.y; acc.z += v.z; acc.w += v.w;
    }
    *(float4*)(agg + (size_t)wave * HDIM + lane * 4) = acc;
}

// -------------------------- attention + head --------------------------------
__global__ void seg_starts(const int* __restrict__ batch, int* __restrict__ starts,
                           int N, int G) {
    int n = blockIdx.x * 256 + threadIdx.x;
    if (n > N) return;
    int b  = (n < N) ? batch[n] : G;
    int bp = (n == 0) ? -1 : batch[n - 1];
    for (int g = bp + 1; g <= b; g++) starts[g] = n;
}

// one wave per node: scores[n] = tanh(h@w1+b1) @ w2 + b2
__global__ __launch_bounds__(256)
void att_scores(const float* __restrict__ h, const float* __restrict__ w1,
                const float* __restrict__ b1, const float* __restrict__ w2,
                const float* __restrict__ b2, float* __restrict__ scores, int N) {
    int node = (blockIdx.x * 256 + threadIdx.x) >> 6;
    int lane = threadIdx.x & 63;
    if (node >= N) return;
    const float* hr = h + (size_t)node * HDIM;
    float acc0 = 0.f, acc1 = 0.f;
    for (int k = 0; k < HDIM; k++) {
        float hv = hr[k];
        acc0 += hv * w1[k * 128 + lane];
        acc1 += hv * w1[k * 128 + 64 + lane];
    }
    float t0 = tanhf(acc0 + b1[lane]);
    float t1 = tanhf(acc1 + b1[64 + lane]);
    float s = t0 * w2[lane] + t1 * w2[64 + lane];
    #pragma unroll
    for (int off = 32; off > 0; off >>= 1) s += __shfl_down(s, off);
    if (lane == 0) scores[node] = s + b2[0];
}

// one block (256 threads) per graph: softmax-weighted pooling
__global__ __launch_bounds__(256)
void att_pool(const float* __restrict__ h, const float* __restrict__ scores,
              const int* __restrict__ starts, float* __restrict__ pooled) {
    int g = blockIdx.x;
    int tid = threadIdx.x;
    int s0 = starts[g], s1 = starts[g + 1];
    __shared__ float red[256];
    __shared__ float e_lds[256];
    float mx = -1e30f;
    for (int n = s0 + tid; n < s1; n += 256) mx = fmaxf(mx, scores[n]);
    red[tid] = mx; __syncthreads();
    for (int off = 128; off > 0; off >>= 1) {
        if (tid < off) red[tid] = fmaxf(red[tid], red[tid + off]);
        __syncthreads();
    }
    mx = red[0]; __syncthreads();
    float se = 0.f;
    for (int n = s0 + tid; n < s1; n += 256) se += expf(scores[n] - mx);
    red[tid] = se; __syncthreads();
    for (int off = 128; off > 0; off >>= 1) {
        if (tid < off) red[tid] += red[tid + off];
        __syncthreads();
    }
    float denom = red[0]; __syncthreads();
    float accp = 0.f;   // thread owns column `tid`
    for (int c0 = s0; c0 < s1; c0 += 256) {
        int n = c0 + tid;
        e_lds[tid] = (n < s1) ? expf(scores[n] - mx) : 0.f;
        __syncthreads();
        int cnt = min(256, s1 - c0);
        for (int j = 0; j < cnt; j++)
            accp += e_lds[j] * h[(size_t)(c0 + j) * HDIM + tid];
        __syncthreads();
    }
    pooled[g * HDIM + tid] = (denom > 0.f) ? accp / denom : 0.f;
}

__global__ __launch_bounds__(128)
void classify(const float* __restrict__ pooled, const float* __restrict__ w1,
              const float* __restrict__ b1, const float* __restrict__ w2,
              const float* __restrict__ b2, float* __restrict__ out) {
    int g = blockIdx.x;
    int tid = threadIdx.x;   // 128 = H/2
    float acc = 0.f;
    for (int k = 0; k < HDIM; k++) acc += pooled[g * HDIM + k] * w1[k * 128 + tid];
    float t = fmaxf(acc + b1[tid], 0.f);
    float v = t * w2[tid];
    __shared__ float red[128];
    red[tid] = v; __syncthreads();
    for (int off = 64; off > 0; off >>= 1) {
        if (tid < off) red[tid] += red[tid + off];
        __syncthreads();
    }
    if (tid == 0) out[g] = red[0] + b2[0];
}

// ---------------------------------------------------------------------------
extern "C" void kernel_launch(void* const* d_in, const int* in_sizes, int n_in,
                              void* d_out, int out_size, void* d_ws, size_t ws_size,
                              hipStream_t stream) {
    const float* x      = (const float*)d_in[0];
    const int*   ei     = (const int*)  d_in[1];
    const int*   batch  = (const int*)  d_in[2];
    const float* proj_w = (const float*)d_in[3];
    const float* proj_b = (const float*)d_in[4];
    const float* conv_w = (const float*)d_in[5];
    const float* w_ih   = (const float*)d_in[6];
    const float* w_hh   = (const float*)d_in[7];
    const float* b_ih   = (const float*)d_in[8];
    const float* b_hh   = (const float*)d_in[9];
    const float* att_w1 = (const float*)d_in[10];
    const float* att_b1 = (const float*)d_in[11];
    const float* att_w2 = (const float*)d_in[12];
    const float* att_b2 = (const float*)d_in[13];
    const float* cls_w1 = (const float*)d_in[14];
    const float* cls_b1 = (const float*)d_in[15];
    const float* cls_w2 = (const float*)d_in[16];
    const float* cls_b2 = (const float*)d_in[17];
    float* out = (float*)d_out;

    char* ws = (char*)d_ws;
    size_t off = 0;
    auto alloc = [&](size_t bytes) -> void* {
        void* p = ws + off;
        off = (off + bytes + 255) & ~(size_t)255;
        return p;
    };
    float* hA     = (float*)alloc((size_t)N_NODES * HDIM * 4);
    float* hB     = (float*)alloc((size_t)N_NODES * HDIM * 4);
    float* mbuf   = (float*)alloc((size_t)N_NODES * HDIM * 4);
    float* agg    = (float*)alloc((size_t)N_NODES * HDIM * 4);
    float* wihT   = (float*)alloc((size_t)HDIM * 3 * HDIM * 4);
    float* whhT   = (float*)alloc((size_t)HDIM * 3 * HDIM * 4);
    int*   rowptr = (int*)  alloc((N_NODES + 1) * 4);
    int*   cursor = (int*)  alloc((N_NODES + 1) * 4);
    int*   deg    = (int*)  alloc(N_NODES * 4);
    int*   csrc   = (int*)  alloc(N_EDGES * 4);
    float* scores = (float*)alloc(N_NODES * 4);
    int*   starts = (int*)  alloc((N_GRAPHS + 1) * 4);
    float* pooled = (float*)alloc((size_t)N_GRAPHS * HDIM * 4);
    (void)ws_size; (void)in_sizes; (void)n_in; (void)out_size;

    // GRU weight transpose ([3H,H] -> [H,3H]) so GEMMs see row-major [K,N]
    transpose_gru<<<dim3((HDIM * 3 * HDIM + 255) / 256), dim3(256), 0, stream>>>(
        w_ih, w_hh, wihT, whhT);

    // input projection + ReLU
    dim3 ggrid((N_NODES + 63) / 64, HDIM / 64);
    gemm_rm<1><<<ggrid, dim3(256), 0, stream>>>(x, proj_w, proj_b, hA,
                                                N_NODES, HDIM, D_IN);

    // CSR by dst (built once per call, reused across all 5 layers)
    hipMemsetAsync(deg, 0, N_NODES * 4, stream);
    edge_count<<<dim3((N_EDGES + 255) / 256), dim3(256), 0, stream>>>(ei, deg, N_EDGES);
    scan_rowptr<<<dim3(1), dim3(1024), 0, stream>>>(deg, rowptr, N_NODES);
    hipMemcpyAsync(cursor, rowptr, (N_NODES + 1) * 4, hipMemcpyDeviceToDevice, stream);
    edge_bucket<<<dim3((N_EDGES + 255) / 256), dim3(256), 0, stream>>>(ei, cursor, csrc, N_EDGES);
    seg_starts<<<dim3((N_NODES + 256) / 256), dim3(256), 0, stream>>>(batch, starts,
                                                                      N_NODES, N_GRAPHS);

    float* hcur = hA;
    float* hnext = hB;
    for (int l = 0; l < L_LAYERS; l++) {
        gemm_rm<0><<<ggrid, dim3(256), 0, stream>>>(hcur, conv_w + (size_t)l * HDIM * HDIM,
                                                    nullptr, mbuf, N_NODES, HDIM, HDIM);
        agg_csr<<<dim3((N_NODES * 64 + 255) / 256), dim3(256), 0, stream>>>(
            mbuf, rowptr, csrc, agg, N_NODES);
        gru_fused<<<ggrid, dim3(256), 0, stream>>>(agg, hcur, wihT, whhT,
                                                   b_ih, b_hh, hnext, N_NODES);
        float* t = hcur; hcur = hnext; hnext = t;
    }

    // attention pooling + classifier
    att_scores<<<dim3((N_NODES * 64 + 255) / 256), dim3(256), 0, stream>>>(
        hcur, att_w1, att_b1, att_w2, att_b2, scores, N_NODES);
    att_pool<<<dim3(N_GRAPHS), dim3(256), 0, stream>>>(hcur, scores, starts, pooled);
    classify<<<dim3(N_GRAPHS), dim3(128), 0, stream>>>(pooled, cls_w1, cls_b1,
                                                       cls_w2, cls_b2, out);
}

// Round 2
// 768.354 us; speedup vs baseline: 3.2459x; 3.2459x over previous
//
#include <hip/hip_runtime.h>
#include <hip/hip_bf16.h>
#include <math.h>

#define N_NODES 20000
#define M_PAD   20096          // 157*128; all row-dim ws buffers padded to this
#define N_EDGES 320000
#define N_GRAPHS 64
#define D_IN 771
#define KP   800               // padded K for projection (multiple of 32)
#define HDIM 256
#define L_LAYERS 5

typedef __attribute__((ext_vector_type(8))) short  bf16x8;
typedef __attribute__((ext_vector_type(4))) float  f32x4;

typedef __attribute__((address_space(3))) void       lds_void;
typedef __attribute__((address_space(1))) const void gconst_void;

__device__ __forceinline__ void gload16(const void* g, void* l) {
    __builtin_amdgcn_global_load_lds((gconst_void*)g, (lds_void*)l, 16, 0, 0);
}

__device__ __forceinline__ unsigned short f2bf(float f) {
    unsigned int u = __float_as_uint(f);
    return (unsigned short)((u + 0x7FFFu + ((u >> 16) & 1u)) >> 16);  // RNE
}
__device__ __forceinline__ float bf2f(unsigned short h) {
    return __uint_as_float(((unsigned int)h) << 16);
}

// ---------------- prep kernels (bf16 casts / transposes, one-time) ----------
__global__ void prep_x(const float* __restrict__ x, unsigned short* __restrict__ xb) {
    size_t i = (size_t)blockIdx.x * 256 + threadIdx.x;     // over 20000*800
    if (i >= (size_t)N_NODES * KP) return;
    int r = (int)(i / KP), k = (int)(i % KP);
    float v = (k < D_IN) ? x[(size_t)r * D_IN + k] : 0.f;
    xb[i] = f2bf(v);
}
__global__ void prep_projw(const float* __restrict__ w, unsigned short* __restrict__ wt) {
    int i = blockIdx.x * 256 + threadIdx.x;                // over 256*800, wt[n][k]
    if (i >= HDIM * KP) return;
    int n = i / KP, k = i % KP;
    wt[i] = f2bf(k < D_IN ? w[(size_t)k * HDIM + n] : 0.f);
}
__global__ void prep_convw(const float* __restrict__ w, unsigned short* __restrict__ wt) {
    int i = blockIdx.x * 256 + threadIdx.x;                // over 5*256*256, wt[l][n][k]
    if (i >= L_LAYERS * HDIM * HDIM) return;
    int l = i / (HDIM * HDIM), rem = i % (HDIM * HDIM);
    int n = rem / HDIM, k = rem % HDIM;
    wt[i] = f2bf(w[(size_t)l * HDIM * HDIM + (size_t)k * HDIM + n]);
}
__global__ void prep_cast2(const float* __restrict__ a, const float* __restrict__ b,
                           unsigned short* __restrict__ ab, unsigned short* __restrict__ bb,
                           int n) {
    int i = blockIdx.x * 256 + threadIdx.x;
    if (i < n) { ab[i] = f2bf(a[i]); bb[i] = f2bf(b[i]); }
}

// ---------------- generic bf16 MFMA GEMM: C[M,256] = A[M,K] @ Bt[N,K]^T -----
// 128x128 tile, 4 waves (2x2), wave tile 64x64 = 4x4 frags of 16x16x32.
// LDS: A tile [128 rows][64B] @0 (8KB), Bt tile [128 rows][64B] @8192 (8KB).
// XOR swizzle (tile_row&3)<<4 applied on global source + ds_read (rule #21).
template<int EPI>   // 0: store Cb only; 1: bias+relu, store Cf and Cb
__global__ __launch_bounds__(256)
void mm128(const unsigned short* __restrict__ A, int lda,
           const unsigned short* __restrict__ Bt, int ldb,
           const float* __restrict__ bias,
           float* __restrict__ Cf, unsigned short* __restrict__ Cb, int nk) {
    __shared__ char lds[16384];
    const int tid = threadIdx.x;
    const int lane = tid & 63, wave = tid >> 6;
    const int wm = wave >> 1, wn = wave & 1;
    const int row0 = blockIdx.x * 128, col0 = blockIdx.y * 128;
    const int lr = lane >> 2;                  // row within 16-row chunk
    const int klog = ((lane & 3) * 16) ^ ((lr & 3) << 4);  // swizzled src byte off
    const int kle = klog >> 1;                 // in elements

    f32x4 acc[4][4];
    #pragma unroll
    for (int i = 0; i < 4; i++)
        #pragma unroll
        for (int j = 0; j < 4; j++) acc[i][j] = (f32x4){0.f, 0.f, 0.f, 0.f};

    for (int ks = 0; ks < nk; ++ks) {
        // stage: each wave loads A chunks {2w,2w+1} and B chunks {2w,2w+1} (1KB each)
        #pragma unroll
        for (int j = 0; j < 2; ++j) {
            int c = wave * 2 + j;
            const unsigned short* sa = A + (size_t)(row0 + c * 16 + lr) * lda + ks * 32 + kle;
            gload16(sa, lds + c * 1024);
            const unsigned short* sb = Bt + (size_t)(col0 + c * 16 + lr) * ldb + ks * 32 + kle;
            gload16(sb, lds + 8192 + c * 1024);
        }
        __syncthreads();
        bf16x8 af[4], bf[4];
        #pragma unroll
        for (int f = 0; f < 4; ++f) {
            int r = wm * 64 + f * 16 + (lane & 15);
            int kl = ((lane >> 4) * 16) ^ ((r & 3) << 4);
            af[f] = *(const bf16x8*)(lds + r * 64 + kl);
            int cb = wn * 64 + f * 16 + (lane & 15);
            int kl2 = ((lane >> 4) * 16) ^ ((cb & 3) << 4);
            bf[f] = *(const bf16x8*)(lds + 8192 + cb * 64 + kl2);
        }
        #pragma unroll
        for (int i = 0; i < 4; i++)
            #pragma unroll
            for (int j = 0; j < 4; j++)
                acc[i][j] = __builtin_amdgcn_mfma_f32_16x16x32_bf16(af[i], bf[j], acc[i][j], 0, 0, 0);
        __syncthreads();
    }
    // epilogue: C row=(lane>>4)*4+ri, col=lane&15 within each 16x16 frag
    #pragma unroll
    for (int i = 0; i < 4; i++) {
        #pragma unroll
        for (int j = 0; j < 4; j++) {
            int cc = col0 + wn * 64 + j * 16 + (lane & 15);
            #pragma unroll
            for (int ri = 0; ri < 4; ++ri) {
                int rr = row0 + wm * 64 + i * 16 + (lane >> 4) * 4 + ri;
                float v = acc[i][j][ri];
                if (EPI == 1) { v += bias[cc]; v = fmaxf(v, 0.f); }
                if (EPI == 1) Cf[(size_t)rr * HDIM + cc] = v;
                Cb[(size_t)rr * HDIM + cc] = f2bf(v);
            }
        }
    }
}

// ---------------- fused GRU: 6 GEMMs (gi/gh x r,z,n) + gates ----------------
// 64(M)x64(N-slab) tile of h_new; 4 waves 2x2, wave tile 32x32 per GEMM set.
// LDS: Aagg[64][64B]@0, Ah@4096, 6x Bt[64][64B]@8192+t*4096  => 32KB.
__global__ __launch_bounds__(256)
void gru_mfma(const unsigned short* __restrict__ aggb, const unsigned short* __restrict__ hb,
              const float* __restrict__ hf,
              const unsigned short* __restrict__ wih, const unsigned short* __restrict__ whh,
              const float* __restrict__ bih, const float* __restrict__ bhh,
              float* __restrict__ hfN, unsigned short* __restrict__ hbN) {
    __shared__ char lds[32768];
    const int tid = threadIdx.x;
    const int lane = tid & 63, wave = tid >> 6;
    const int wm = wave >> 1, wn = wave & 1;
    const int row0 = blockIdx.x * 64, col0 = blockIdx.y * 64;
    const int lr = lane >> 2;
    const int klog = ((lane & 3) * 16) ^ ((lr & 3) << 4);
    const int kle = klog >> 1;

    f32x4 acc[3][2][2][2];
    #pragma unroll
    for (int s = 0; s < 3; s++)
        #pragma unroll
        for (int m = 0; m < 2; m++)
            #pragma unroll
            for (int i = 0; i < 2; i++)
                #pragma unroll
                for (int j = 0; j < 2; j++) acc[s][m][i][j] = (f32x4){0.f, 0.f, 0.f, 0.f};

    for (int ks = 0; ks < 8; ++ks) {
        #pragma unroll
        for (int j = 0; j < 8; ++j) {
            int c = wave + j * 4;              // 32 chunks of 1KB
            const unsigned short* src;
            if (c < 4)      src = aggb + (size_t)(row0 + c * 16 + lr) * HDIM;
            else if (c < 8) src = hb   + (size_t)(row0 + (c - 4) * 16 + lr) * HDIM;
            else {
                int t = (c - 8) >> 2, c4 = (c - 8) & 3;
                int s = t >> 1;
                const unsigned short* W = (t & 1) ? whh : wih;
                src = W + (size_t)(s * HDIM + col0 + c4 * 16 + lr) * HDIM;
            }
            gload16(src + ks * 32 + kle, lds + c * 1024);
        }
        __syncthreads();
        bf16x8 a[2][2];
        #pragma unroll
        for (int m = 0; m < 2; m++)
            #pragma unroll
            for (int fr = 0; fr < 2; fr++) {
                int r = wm * 32 + fr * 16 + (lane & 15);
                int kl = ((lane >> 4) * 16) ^ ((r & 3) << 4);
                a[m][fr] = *(const bf16x8*)(lds + m * 4096 + r * 64 + kl);
            }
        #pragma unroll
        for (int s = 0; s < 3; s++) {
            bf16x8 b[2][2];
            #pragma unroll
            for (int m = 0; m < 2; m++)
                #pragma unroll
                for (int fc = 0; fc < 2; fc++) {
                    int r = wn * 32 + fc * 16 + (lane & 15);
                    int kl = ((lane >> 4) * 16) ^ ((r & 3) << 4);
                    b[m][fc] = *(const bf16x8*)(lds + 8192 + (s * 2 + m) * 4096 + r * 64 + kl);
                }
            #pragma unroll
            for (int m = 0; m < 2; m++)
                #pragma unroll
                for (int fr = 0; fr < 2; fr++)
                    #pragma unroll
                    for (int fc = 0; fc < 2; fc++)
                        acc[s][m][fr][fc] = __builtin_amdgcn_mfma_f32_16x16x32_bf16(
                            a[m][fr], b[m][fc], acc[s][m][fr][fc], 0, 0, 0);
        }
        __syncthreads();
    }
    #pragma unroll
    for (int fr = 0; fr < 2; fr++)
        #pragma unroll
        for (int fc = 0; fc < 2; fc++) {
            int cc = col0 + wn * 32 + fc * 16 + (lane & 15);
            float bir = bih[cc],            bhr = bhh[cc];
            float biz = bih[HDIM + cc],     bhz = bhh[HDIM + cc];
            float bin = bih[2 * HDIM + cc], bhn = bhh[2 * HDIM + cc];
            #pragma unroll
            for (int ri = 0; ri < 4; ++ri) {
                int rr = row0 + wm * 32 + fr * 16 + (lane >> 4) * 4 + ri;
                float xr = acc[0][0][fr][fc][ri] + bir + acc[0][1][fr][fc][ri] + bhr;
                float xz = acc[1][0][fr][fc][ri] + biz + acc[1][1][fr][fc][ri] + bhz;
                float gn = acc[2][0][fr][fc][ri] + bin;
                float hn = acc[2][1][fr][fc][ri] + bhn;
                float r_ = 1.f / (1.f + expf(-xr));
                float z_ = 1.f / (1.f + expf(-xz));
                float n_ = tanhf(gn + r_ * hn);
                float ho = hf[(size_t)rr * HDIM + cc];
                float v  = (1.f - z_) * n_ + z_ * ho;
                hfN[(size_t)rr * HDIM + cc] = v;
                hbN[(size_t)rr * HDIM + cc] = f2bf(v);
            }
        }
}

// -------------------------- CSR build (unchanged) ---------------------------
__global__ void edge_count(const int* __restrict__ ei, int* __restrict__ deg, int E) {
    int e = blockIdx.x * 256 + threadIdx.x;
    if (e < E) atomicAdd(&deg[ei[E + e]], 1);
}
__global__ __launch_bounds__(1024)
void scan_rowptr(const int* __restrict__ deg, int* __restrict__ rowptr, int N) {
    __shared__ int bs[1024];
    const int tid = threadIdx.x;
    const int CH = (N + 1023) / 1024;
    const int base = tid * CH;
    int sum = 0;
    for (int i = 0; i < CH; i++) { int idx = base + i; sum += (idx < N) ? deg[idx] : 0; }
    bs[tid] = sum; __syncthreads();
    for (int off = 1; off < 1024; off <<= 1) {
        int v = (tid >= off) ? bs[tid - off] : 0;
        __syncthreads();
        bs[tid] += v;
        __syncthreads();
    }
    int run = (tid > 0) ? bs[tid - 1] : 0;
    for (int i = 0; i < CH; i++) {
        int idx = base + i;
        if (idx < N) { rowptr[idx] = run; run += deg[idx]; }
    }
    if (tid == 0) rowptr[N] = bs[1023];
}
__global__ void edge_bucket(const int* __restrict__ ei, int* __restrict__ cursor,
                            int* __restrict__ csrc, int E) {
    int e = blockIdx.x * 256 + threadIdx.x;
    if (e < E) {
        int d = ei[E + e];
        int p = atomicAdd(&cursor[d], 1);
        csrc[p] = ei[e];
    }
}

// one wave per node, bf16 m rows (512B each): agg = sum of in-edge m[src]
__global__ __launch_bounds__(256)
void agg_bf16(const unsigned short* __restrict__ m, const int* __restrict__ rowptr,
              const int* __restrict__ csrc, unsigned short* __restrict__ agg, int N) {
    int wv = (blockIdx.x * 256 + threadIdx.x) >> 6;
    int lane = threadIdx.x & 63;
    if (wv >= N) return;
    int s0 = rowptr[wv], s1 = rowptr[wv + 1];
    float a0 = 0.f, a1 = 0.f, a2 = 0.f, a3 = 0.f;
    for (int e = s0; e < s1; e++) {
        const unsigned short* r = m + (size_t)csrc[e] * HDIM + lane * 4;
        ushort4 v = *(const ushort4*)r;
        a0 += bf2f(v.x); a1 += bf2f(v.y); a2 += bf2f(v.z); a3 += bf2f(v.w);
    }
    ushort4 o = { f2bf(a0), f2bf(a1), f2bf(a2), f2bf(a3) };
    *(ushort4*)(agg + (size_t)wv * HDIM + lane * 4) = o;
}

// -------------------------- attention + head (fp32, unchanged) --------------
__global__ void seg_starts(const int* __restrict__ batch, int* __restrict__ starts,
                           int N, int G) {
    int n = blockIdx.x * 256 + threadIdx.x;
    if (n > N) return;
    int b  = (n < N) ? batch[n] : G;
    int bp = (n == 0) ? -1 : batch[n - 1];
    for (int g = bp + 1; g <= b; g++) starts[g] = n;
}
__global__ __launch_bounds__(256)
void att_scores(const float* __restrict__ h, const float* __restrict__ w1,
                const float* __restrict__ b1, const float* __restrict__ w2,
                const float* __restrict__ b2, float* __restrict__ scores, int N) {
    int node = (blockIdx.x * 256 + threadIdx.x) >> 6;
    int lane = threadIdx.x & 63;
    if (node >= N) return;
    const float* hr = h + (size_t)node * HDIM;
    float acc0 = 0.f, acc1 = 0.f;
    for (int k = 0; k < HDIM; k++) {
        float hv = hr[k];
        acc0 += hv * w1[k * 128 + lane];
        acc1 += hv * w1[k * 128 + 64 + lane];
    }
    float t0 = tanhf(acc0 + b1[lane]);
    float t1 = tanhf(acc1 + b1[64 + lane]);
    float s = t0 * w2[lane] + t1 * w2[64 + lane];
    #pragma unroll
    for (int off = 32; off > 0; off >>= 1) s += __shfl_down(s, off);
    if (lane == 0) scores[node] = s + b2[0];
}
__global__ __launch_bounds__(256)
void att_pool(const float* __restrict__ h, const float* __restrict__ scores,
              const int* __restrict__ starts, float* __restrict__ pooled) {
    int g = blockIdx.x;
    int tid = threadIdx.x;
    int s0 = starts[g], s1 = starts[g + 1];
    __shared__ float red[256];
    __shared__ float e_lds[256];
    float mx = -1e30f;
    for (int n = s0 + tid; n < s1; n += 256) mx = fmaxf(mx, scores[n]);
    red[tid] = mx; __syncthreads();
    for (int off = 128; off > 0; off >>= 1) {
        if (tid < off) red[tid] = fmaxf(red[tid], red[tid + off]);
        __syncthreads();
    }
    mx = red[0]; __syncthreads();
    float se = 0.f;
    for (int n = s0 + tid; n < s1; n += 256) se += expf(scores[n] - mx);
    red[tid] = se; __syncthreads();
    for (int off = 128; off > 0; off >>= 1) {
        if (tid < off) red[tid] += red[tid + off];
        __syncthreads();
    }
    float denom = red[0]; __syncthreads();
    float accp = 0.f;
    for (int c0 = s0; c0 < s1; c0 += 256) {
        int n = c0 + tid;
        e_lds[tid] = (n < s1) ? expf(scores[n] - mx) : 0.f;
        __syncthreads();
        int cnt = min(256, s1 - c0);
        for (int j = 0; j < cnt; j++)
            accp += e_lds[j] * h[(size_t)(c0 + j) * HDIM + tid];
        __syncthreads();
    }
    pooled[g * HDIM + tid] = (denom > 0.f) ? accp / denom : 0.f;
}
__global__ __launch_bounds__(128)
void classify(const float* __restrict__ pooled, const float* __restrict__ w1,
              const float* __restrict__ b1, const float* __restrict__ w2,
              const float* __restrict__ b2, float* __restrict__ out) {
    int g = blockIdx.x;
    int tid = threadIdx.x;
    float acc = 0.f;
    for (int k = 0; k < HDIM; k++) acc += pooled[g * HDIM + k] * w1[k * 128 + tid];
    float t = fmaxf(acc + b1[tid], 0.f);
    float v = t * w2[tid];
    __shared__ float red[128];
    red[tid] = v; __syncthreads();
    for (int off = 64; off > 0; off >>= 1) {
        if (tid < off) red[tid] += red[tid + off];
        __syncthreads();
    }
    if (tid == 0) out[g] = red[0] + b2[0];
}

// ---------------------------------------------------------------------------
extern "C" void kernel_launch(void* const* d_in, const int* in_sizes, int n_in,
                              void* d_out, int out_size, void* d_ws, size_t ws_size,
                              hipStream_t stream) {
    const float* x      = (const float*)d_in[0];
    const int*   ei     = (const int*)  d_in[1];
    const int*   batch  = (const int*)  d_in[2];
    const float* proj_w = (const float*)d_in[3];
    const float* proj_b = (const float*)d_in[4];
    const float* conv_w = (const float*)d_in[5];
    const float* w_ih   = (const float*)d_in[6];
    const float* w_hh   = (const float*)d_in[7];
    const float* b_ih   = (const float*)d_in[8];
    const float* b_hh   = (const float*)d_in[9];
    const float* att_w1 = (const float*)d_in[10];
    const float* att_b1 = (const float*)d_in[11];
    const float* att_w2 = (const float*)d_in[12];
    const float* att_b2 = (const float*)d_in[13];
    const float* cls_w1 = (const float*)d_in[14];
    const float* cls_b1 = (const float*)d_in[15];
    const float* cls_w2 = (const float*)d_in[16];
    const float* cls_b2 = (const float*)d_in[17];
    float* out = (float*)d_out;

    char* ws = (char*)d_ws;
    size_t off = 0;
    auto alloc = [&](size_t bytes) -> void* {
        void* p = ws + off;
        off = (off + bytes + 255) & ~(size_t)255;
        return p;
    };
    // persistent
    float*          hf0    = (float*)         alloc((size_t)M_PAD * HDIM * 4);
    unsigned short* hb0    = (unsigned short*)alloc((size_t)M_PAD * HDIM * 2);
    unsigned short* hb1    = (unsigned short*)alloc((size_t)M_PAD * HDIM * 2);
    unsigned short* wihb   = (unsigned short*)alloc((size_t)3 * HDIM * HDIM * 2);
    unsigned short* whhb   = (unsigned short*)alloc((size_t)3 * HDIM * HDIM * 2);
    unsigned short* projWT = (unsigned short*)alloc((size_t)HDIM * KP * 2);
    unsigned short* convT  = (unsigned short*)alloc((size_t)L_LAYERS * HDIM * HDIM * 2);
    int*   rowptr = (int*)  alloc((N_NODES + 1) * 4);
    int*   cursor = (int*)  alloc((N_NODES + 1) * 4);
    int*   deg    = (int*)  alloc(N_NODES * 4);
    int*   csrc   = (int*)  alloc(N_EDGES * 4);
    float* scores = (float*)alloc(N_NODES * 4);
    int*   starts = (int*)  alloc((N_GRAPHS + 1) * 4);
    float* pooled = (float*)alloc((size_t)N_GRAPHS * HDIM * 4);
    // union region: xb (proj phase) overlaps {mb, aggb, hf1} (layer phase)
    char* U = (char*)alloc((size_t)M_PAD * KP * 2 > (size_t)M_PAD * HDIM * (2 + 2 + 4)
                               ? (size_t)M_PAD * KP * 2
                               : (size_t)M_PAD * HDIM * (2 + 2 + 4));
    unsigned short* xb   = (unsigned short*)U;
    unsigned short* mb   = (unsigned short*)U;
    unsigned short* aggb = (unsigned short*)(U + (size_t)M_PAD * HDIM * 2);
    float*          hf1  = (float*)         (U + (size_t)M_PAD * HDIM * 4);
    (void)ws_size; (void)in_sizes; (void)n_in; (void)out_size;

    // ---- one-time prep ----
    prep_x     <<<dim3((N_NODES * KP) / 256), dim3(256), 0, stream>>>(x, xb);
    prep_projw <<<dim3((HDIM * KP) / 256), dim3(256), 0, stream>>>(proj_w, projWT);
    prep_convw <<<dim3((L_LAYERS * HDIM * HDIM) / 256), dim3(256), 0, stream>>>(conv_w, convT);
    prep_cast2 <<<dim3((3 * HDIM * HDIM) / 256), dim3(256), 0, stream>>>(
        w_ih, w_hh, wihb, whhb, 3 * HDIM * HDIM);

    // ---- input projection (+bias+relu) -> hf0 (f32) + hb0 (bf16) ----
    mm128<1><<<dim3(M_PAD / 128, 2), dim3(256), 0, stream>>>(
        xb, KP, projWT, KP, proj_b, hf0, hb0, KP / 32);

    // ---- CSR by dst ----
    hipMemsetAsync(deg, 0, N_NODES * 4, stream);
    edge_count<<<dim3((N_EDGES + 255) / 256), dim3(256), 0, stream>>>(ei, deg, N_EDGES);
    scan_rowptr<<<dim3(1), dim3(1024), 0, stream>>>(deg, rowptr, N_NODES);
    hipMemcpyAsync(cursor, rowptr, (N_NODES + 1) * 4, hipMemcpyDeviceToDevice, stream);
    edge_bucket<<<dim3((N_EDGES + 255) / 256), dim3(256), 0, stream>>>(ei, cursor, csrc, N_EDGES);
    seg_starts<<<dim3((N_NODES + 256) / 256), dim3(256), 0, stream>>>(batch, starts,
                                                                      N_NODES, N_GRAPHS);

    // ---- 5 message-passing layers ----
    float*          hfc = hf0;  float*          hfn = hf1;
    unsigned short* hbc = hb0;  unsigned short* hbn = hb1;
    for (int l = 0; l < L_LAYERS; l++) {
        mm128<0><<<dim3(M_PAD / 128, 2), dim3(256), 0, stream>>>(
            hbc, HDIM, convT + (size_t)l * HDIM * HDIM, HDIM, nullptr, nullptr, mb, HDIM / 32);
        agg_bf16<<<dim3((N_NODES * 64) / 256), dim3(256), 0, stream>>>(
            mb, rowptr, csrc, aggb, N_NODES);
        gru_mfma<<<dim3(313, 4), dim3(256), 0, stream>>>(
            aggb, hbc, hfc, wihb, whhb, b_ih, b_hh, hfn, hbn);
        float* tf = hfc; hfc = hfn; hfn = tf;
        unsigned short* tb = hbc; hbc = hbn; hbn = tb;
    }

    // ---- attention pooling + classifier (fp32 on final h) ----
    att_scores<<<dim3((N_NODES * 64) / 256), dim3(256), 0, stream>>>(
        hfc, att_w1, att_b1, att_w2, att_b2, scores, N_NODES);
    att_pool<<<dim3(N_GRAPHS), dim3(256), 0, stream>>>(hfc, scores, starts, pooled);
    classify<<<dim3(N_GRAPHS), dim3(128), 0, stream>>>(pooled, cls_w1, cls_b1,
                                                       cls_w2, cls_b2, out);
}

// Round 3
// 738.142 us; speedup vs baseline: 3.3787x; 1.0409x over previous
//
#include <hip/hip_runtime.h>
#include <hip/hip_bf16.h>
#include <math.h>

#define N_NODES 20000
#define M_PAD   20096          // 157*128; all row-dim ws buffers padded to this
#define N_EDGES 320000
#define N_GRAPHS 64
#define D_IN 771
#define KP   800               // padded K for projection (multiple of 32)
#define HDIM 256
#define L_LAYERS 5

typedef __attribute__((ext_vector_type(8))) short  bf16x8;
typedef __attribute__((ext_vector_type(4))) float  f32x4;

typedef __attribute__((address_space(3))) void       lds_void;
typedef __attribute__((address_space(1))) const void gconst_void;

__device__ __forceinline__ void gload16(const void* g, void* l) {
    __builtin_amdgcn_global_load_lds((gconst_void*)g, (lds_void*)l, 16, 0, 0);
}

__device__ __forceinline__ unsigned short f2bf(float f) {
    unsigned int u = __float_as_uint(f);
    return (unsigned short)((u + 0x7FFFu + ((u >> 16) & 1u)) >> 16);  // RNE
}
__device__ __forceinline__ float bf2f(unsigned short h) {
    return __uint_as_float(((unsigned int)h) << 16);
}

// ---------------- prep kernels (bf16 casts / transposes, one-time) ----------
__global__ void prep_x(const float* __restrict__ x, unsigned short* __restrict__ xb) {
    size_t i = (size_t)blockIdx.x * 256 + threadIdx.x;     // over 20000*800
    if (i >= (size_t)N_NODES * KP) return;
    int r = (int)(i / KP), k = (int)(i % KP);
    float v = (k < D_IN) ? x[(size_t)r * D_IN + k] : 0.f;
    xb[i] = f2bf(v);
}
__global__ void prep_projw(const float* __restrict__ w, unsigned short* __restrict__ wt) {
    int i = blockIdx.x * 256 + threadIdx.x;                // over 256*800, wt[n][k]
    if (i >= HDIM * KP) return;
    int n = i / KP, k = i % KP;
    wt[i] = f2bf(k < D_IN ? w[(size_t)k * HDIM + n] : 0.f);
}
__global__ void prep_convw(const float* __restrict__ w, unsigned short* __restrict__ wt) {
    int i = blockIdx.x * 256 + threadIdx.x;                // over 5*256*256, wt[l][n][k]
    if (i >= L_LAYERS * HDIM * HDIM) return;
    int l = i / (HDIM * HDIM), rem = i % (HDIM * HDIM);
    int n = rem / HDIM, k = rem % HDIM;
    wt[i] = f2bf(w[(size_t)l * HDIM * HDIM + (size_t)k * HDIM + n]);
}
__global__ void prep_cast2(const float* __restrict__ a, const float* __restrict__ b,
                           unsigned short* __restrict__ ab, unsigned short* __restrict__ bb,
                           int n) {
    int i = blockIdx.x * 256 + threadIdx.x;
    if (i < n) { ab[i] = f2bf(a[i]); bb[i] = f2bf(b[i]); }
}

// ---------------- generic bf16 MFMA GEMM: C[M,256] = A[M,K] @ Bt[N,K]^T -----
// 128x128 tile, 4 waves (2x2), wave tile 64x64 = 4x4 frags of 16x16x32.
template<int EPI>   // 0: store Cb only; 1: bias+relu, store Cf and Cb
__global__ __launch_bounds__(256)
void mm128(const unsigned short* __restrict__ A, int lda,
           const unsigned short* __restrict__ Bt, int ldb,
           const float* __restrict__ bias,
           float* __restrict__ Cf, unsigned short* __restrict__ Cb, int nk) {
    __shared__ char lds[16384];
    const int tid = threadIdx.x;
    const int lane = tid & 63, wave = tid >> 6;
    const int wm = wave >> 1, wn = wave & 1;
    const int row0 = blockIdx.x * 128, col0 = blockIdx.y * 128;
    const int lr = lane >> 2;                  // row within 16-row chunk
    const int klog = ((lane & 3) * 16) ^ ((lr & 3) << 4);  // swizzled src byte off
    const int kle = klog >> 1;                 // in elements

    f32x4 acc[4][4];
    #pragma unroll
    for (int i = 0; i < 4; i++)
        #pragma unroll
        for (int j = 0; j < 4; j++) acc[i][j] = (f32x4){0.f, 0.f, 0.f, 0.f};

    for (int ks = 0; ks < nk; ++ks) {
        #pragma unroll
        for (int j = 0; j < 2; ++j) {
            int c = wave * 2 + j;
            const unsigned short* sa = A + (size_t)(row0 + c * 16 + lr) * lda + ks * 32 + kle;
            gload16(sa, lds + c * 1024);
            const unsigned short* sb = Bt + (size_t)(col0 + c * 16 + lr) * ldb + ks * 32 + kle;
            gload16(sb, lds + 8192 + c * 1024);
        }
        __syncthreads();
        bf16x8 af[4], bf[4];
        #pragma unroll
        for (int f = 0; f < 4; ++f) {
            int r = wm * 64 + f * 16 + (lane & 15);
            int kl = ((lane >> 4) * 16) ^ ((r & 3) << 4);
            af[f] = *(const bf16x8*)(lds + r * 64 + kl);
            int cb = wn * 64 + f * 16 + (lane & 15);
            int kl2 = ((lane >> 4) * 16) ^ ((cb & 3) << 4);
            bf[f] = *(const bf16x8*)(lds + 8192 + cb * 64 + kl2);
        }
        #pragma unroll
        for (int i = 0; i < 4; i++)
            #pragma unroll
            for (int j = 0; j < 4; j++)
                acc[i][j] = __builtin_amdgcn_mfma_f32_16x16x32_bf16(af[i], bf[j], acc[i][j], 0, 0, 0);
        __syncthreads();
    }
    #pragma unroll
    for (int i = 0; i < 4; i++) {
        #pragma unroll
        for (int j = 0; j < 4; j++) {
            int cc = col0 + wn * 64 + j * 16 + (lane & 15);
            #pragma unroll
            for (int ri = 0; ri < 4; ++ri) {
                int rr = row0 + wm * 64 + i * 16 + (lane >> 4) * 4 + ri;
                float v = acc[i][j][ri];
                if (EPI == 1) { v += bias[cc]; v = fmaxf(v, 0.f); }
                if (EPI == 1) Cf[(size_t)rr * HDIM + cc] = v;
                Cb[(size_t)rr * HDIM + cc] = f2bf(v);
            }
        }
    }
}

// ---------------- fused GRU v2: 128x64 tile, 8 waves (4x2) ------------------
// 6 GEMM sets (gi/gh x r,z,n); wave tile 32x32 per set.
// LDS: Aagg[128][64B]@0, Ah@8192, 6x B[64][64B]@16384+t*4096 => 40KB.
__global__ __launch_bounds__(512)
void gru_mfma(const unsigned short* __restrict__ aggb, const unsigned short* __restrict__ hb,
              const float* __restrict__ hf,
              const unsigned short* __restrict__ wih, const unsigned short* __restrict__ whh,
              const float* __restrict__ bih, const float* __restrict__ bhh,
              float* __restrict__ hfN, unsigned short* __restrict__ hbN) {
    __shared__ char lds[40960];
    const int tid = threadIdx.x;
    const int lane = tid & 63, wave = tid >> 6;   // 8 waves
    const int wm = wave >> 1, wn = wave & 1;      // 4 x 2
    const int row0 = blockIdx.x * 128, col0 = blockIdx.y * 64;
    const int lr = lane >> 2;
    const int klog = ((lane & 3) * 16) ^ ((lr & 3) << 4);
    const int kle = klog >> 1;

    f32x4 acc[3][2][2][2];
    #pragma unroll
    for (int s = 0; s < 3; s++)
        #pragma unroll
        for (int m = 0; m < 2; m++)
            #pragma unroll
            for (int i = 0; i < 2; i++)
                #pragma unroll
                for (int j = 0; j < 2; j++) acc[s][m][i][j] = (f32x4){0.f, 0.f, 0.f, 0.f};

    for (int ks = 0; ks < 8; ++ks) {
        // 40 chunks of 1KB: 8 Aagg, 8 Ah, 24 B(6 slabs x 4). 5 per wave.
        #pragma unroll
        for (int j = 0; j < 5; ++j) {
            int c = wave + j * 8;
            const unsigned short* src;
            if (c < 8)       src = aggb + (size_t)(row0 + c * 16 + lr) * HDIM;
            else if (c < 16) src = hb   + (size_t)(row0 + (c - 16 + 8) * 16 + lr) * HDIM;
            else {
                int t = (c - 16) >> 2, c4 = (c - 16) & 3;
                int s = t >> 1;
                const unsigned short* W = (t & 1) ? whh : wih;
                src = W + (size_t)(s * HDIM + col0 + c4 * 16 + lr) * HDIM;
            }
            gload16(src + ks * 32 + kle, lds + c * 1024);
        }
        __syncthreads();
        bf16x8 a[2][2];
        #pragma unroll
        for (int m = 0; m < 2; m++)
            #pragma unroll
            for (int fr = 0; fr < 2; fr++) {
                int r = wm * 32 + fr * 16 + (lane & 15);
                int kl = ((lane >> 4) * 16) ^ ((r & 3) << 4);
                a[m][fr] = *(const bf16x8*)(lds + m * 8192 + r * 64 + kl);
            }
        #pragma unroll
        for (int s = 0; s < 3; s++) {
            bf16x8 b[2][2];
            #pragma unroll
            for (int m = 0; m < 2; m++)
                #pragma unroll
                for (int fc = 0; fc < 2; fc++) {
                    int rb = wn * 32 + fc * 16 + (lane & 15);
                    int kl = ((lane >> 4) * 16) ^ ((rb & 3) << 4);
                    b[m][fc] = *(const bf16x8*)(lds + 16384 + (s * 2 + m) * 4096 + rb * 64 + kl);
                }
            #pragma unroll
            for (int m = 0; m < 2; m++)
                #pragma unroll
                for (int fr = 0; fr < 2; fr++)
                    #pragma unroll
                    for (int fc = 0; fc < 2; fc++)
                        acc[s][m][fr][fc] = __builtin_amdgcn_mfma_f32_16x16x32_bf16(
                            a[m][fr], b[m][fc], acc[s][m][fr][fc], 0, 0, 0);
        }
        __syncthreads();
    }
    #pragma unroll
    for (int fr = 0; fr < 2; fr++)
        #pragma unroll
        for (int fc = 0; fc < 2; fc++) {
            int cc = col0 + wn * 32 + fc * 16 + (lane & 15);
            float bir = bih[cc],            bhr = bhh[cc];
            float biz = bih[HDIM + cc],     bhz = bhh[HDIM + cc];
            float bin = bih[2 * HDIM + cc], bhn = bhh[2 * HDIM + cc];
            #pragma unroll
            for (int ri = 0; ri < 4; ++ri) {
                int rr = row0 + wm * 32 + fr * 16 + (lane >> 4) * 4 + ri;
                float xr = acc[0][0][fr][fc][ri] + bir + acc[0][1][fr][fc][ri] + bhr;
                float xz = acc[1][0][fr][fc][ri] + biz + acc[1][1][fr][fc][ri] + bhz;
                float gn = acc[2][0][fr][fc][ri] + bin;
                float hn = acc[2][1][fr][fc][ri] + bhn;
                float r_ = 1.f / (1.f + expf(-xr));
                float z_ = 1.f / (1.f + expf(-xz));
                float n_ = tanhf(gn + r_ * hn);
                float ho = hf[(size_t)rr * HDIM + cc];
                float v  = (1.f - z_) * n_ + z_ * ho;
                hfN[(size_t)rr * HDIM + cc] = v;
                hbN[(size_t)rr * HDIM + cc] = f2bf(v);
            }
        }
}

// -------------------------- CSR build ---------------------------------------
__global__ void edge_count(const int* __restrict__ ei, int* __restrict__ deg, int E) {
    int e = blockIdx.x * 256 + threadIdx.x;
    if (e < E) atomicAdd(&deg[ei[E + e]], 1);
}
__global__ __launch_bounds__(1024)
void scan_rowptr(const int* __restrict__ deg, int* __restrict__ rowptr, int N) {
    __shared__ int bs[1024];
    const int tid = threadIdx.x;
    const int CH = (N + 1023) / 1024;
    const int base = tid * CH;
    int sum = 0;
    for (int i = 0; i < CH; i++) { int idx = base + i; sum += (idx < N) ? deg[idx] : 0; }
    bs[tid] = sum; __syncthreads();
    for (int off = 1; off < 1024; off <<= 1) {
        int v = (tid >= off) ? bs[tid - off] : 0;
        __syncthreads();
        bs[tid] += v;
        __syncthreads();
    }
    int run = (tid > 0) ? bs[tid - 1] : 0;
    for (int i = 0; i < CH; i++) {
        int idx = base + i;
        if (idx < N) { rowptr[idx] = run; run += deg[idx]; }
    }
    if (tid == 0) rowptr[N] = bs[1023];
}
__global__ void edge_bucket(const int* __restrict__ ei, int* __restrict__ cursor,
                            int* __restrict__ csrc, int E) {
    int e = blockIdx.x * 256 + threadIdx.x;
    if (e < E) {
        int d = ei[E + e];
        int p = atomicAdd(&cursor[d], 1);
        csrc[p] = ei[e];
    }
}

// one wave per node, bf16 m rows (512B each): agg = sum of in-edge m[src]
__global__ __launch_bounds__(256)
void agg_bf16(const unsigned short* __restrict__ m, const int* __restrict__ rowptr,
              const int* __restrict__ csrc, unsigned short* __restrict__ agg, int N) {
    int wv = (blockIdx.x * 256 + threadIdx.x) >> 6;
    int lane = threadIdx.x & 63;
    if (wv >= N) return;
    int s0 = rowptr[wv], s1 = rowptr[wv + 1];
    float a0 = 0.f, a1 = 0.f, a2 = 0.f, a3 = 0.f;
    for (int e = s0; e < s1; e++) {
        const unsigned short* r = m + (size_t)csrc[e] * HDIM + lane * 4;
        ushort4 v = *(const ushort4*)r;
        a0 += bf2f(v.x); a1 += bf2f(v.y); a2 += bf2f(v.z); a3 += bf2f(v.w);
    }
    ushort4 o = { f2bf(a0), f2bf(a1), f2bf(a2), f2bf(a3) };
    *(ushort4*)(agg + (size_t)wv * HDIM + lane * 4) = o;
}

// -------------------------- attention + head --------------------------------
__global__ void seg_starts(const int* __restrict__ batch, int* __restrict__ starts,
                           int N, int G) {
    int n = blockIdx.x * 256 + threadIdx.x;
    if (n > N) return;
    int b  = (n < N) ? batch[n] : G;
    int bp = (n == 0) ? -1 : batch[n - 1];
    for (int g = bp + 1; g <= b; g++) starts[g] = n;
}

// fused fp32 GEMM scores: 64 rows x 128 cols per block, tanh*w2 + row-reduce.
__global__ __launch_bounds__(256)
void att_scores2(const float* __restrict__ h, const float* __restrict__ w1,
                 const float* __restrict__ b1, const float* __restrict__ w2,
                 const float* __restrict__ b2, float* __restrict__ scores) {
    __shared__ float As[16][68];
    __shared__ float Bs[16][136];
    __shared__ float red[64][17];
    const int tid = threadIdx.x;
    const int row0 = blockIdx.x * 64;
    const int tm = (tid & 15) * 4, tn = (tid >> 4) * 8;
    const int ar = tid >> 2, ac = (tid & 3) * 4;
    const int br = tid >> 4, bc = (tid & 15) * 8;
    float acc[4][8] = {};
    for (int k0 = 0; k0 < HDIM; k0 += 16) {
        float4 av = {0.f, 0.f, 0.f, 0.f};
        int arow = row0 + ar;
        if (arow < N_NODES) av = *(const float4*)(h + (size_t)arow * HDIM + k0 + ac);
        As[ac + 0][ar] = av.x; As[ac + 1][ar] = av.y;
        As[ac + 2][ar] = av.z; As[ac + 3][ar] = av.w;
        *(float4*)&Bs[br][bc]     = *(const float4*)(w1 + (size_t)(k0 + br) * 128 + bc);
        *(float4*)&Bs[br][bc + 4] = *(const float4*)(w1 + (size_t)(k0 + br) * 128 + bc + 4);
        __syncthreads();
        #pragma unroll
        for (int kk = 0; kk < 16; kk++) {
            float4 a4 = *(const float4*)&As[kk][tm];
            float4 b4 = *(const float4*)&Bs[kk][tn];
            float4 c4 = *(const float4*)&Bs[kk][tn + 4];
            float aa[4] = {a4.x, a4.y, a4.z, a4.w};
            float bb[8] = {b4.x, b4.y, b4.z, b4.w, c4.x, c4.y, c4.z, c4.w};
            #pragma unroll
            for (int i = 0; i < 4; i++)
                #pragma unroll
                for (int j = 0; j < 8; j++) acc[i][j] += aa[i] * bb[j];
        }
        __syncthreads();
    }
    #pragma unroll
    for (int i = 0; i < 4; i++) {
        float s = 0.f;
        #pragma unroll
        for (int j = 0; j < 8; j++)
            s += tanhf(acc[i][j] + b1[tn + j]) * w2[tn + j];
        red[tm + i][tid >> 4] = s;
    }
    __syncthreads();
    if (tid < 64) {
        float s = 0.f;
        #pragma unroll
        for (int g = 0; g < 16; g++) s += red[tid][g];
        int n = row0 + tid;
        if (n < N_NODES) scores[n] = s + b2[0];
    }
}

// per-graph max + denom: one wave per graph
__global__ __launch_bounds__(256)
void seg_stats(const float* __restrict__ scores, const int* __restrict__ starts,
               float* __restrict__ gmax, float* __restrict__ gden) {
    int wv = (blockIdx.x * 256 + threadIdx.x) >> 6;
    int lane = threadIdx.x & 63;
    if (wv >= N_GRAPHS) return;
    int s0 = starts[wv], s1 = starts[wv + 1];
    float mx = -1e30f;
    for (int n = s0 + lane; n < s1; n += 64) mx = fmaxf(mx, scores[n]);
    #pragma unroll
    for (int off = 32; off > 0; off >>= 1) mx = fmaxf(mx, __shfl_xor(mx, off));
    float se = 0.f;
    for (int n = s0 + lane; n < s1; n += 64) se += expf(scores[n] - mx);
    #pragma unroll
    for (int off = 32; off > 0; off >>= 1) se += __shfl_xor(se, off);
    if (lane == 0) { gmax[wv] = mx; gden[wv] = se; }
}

__global__ void node_weights(const float* __restrict__ scores, const int* __restrict__ batch,
                             const float* __restrict__ gmax, const float* __restrict__ gden,
                             float* __restrict__ wn) {
    int n = blockIdx.x * 256 + threadIdx.x;
    if (n >= N_NODES) return;
    int g = batch[n];
    float d = gden[g];
    wn[n] = (d > 0.f) ? expf(scores[n] - gmax[g]) / d : 0.f;
}

// deterministic 4-stripe weighted pool: block (g,s) handles nodes n≡s (mod 4)
__global__ __launch_bounds__(256)
void pool_partial(const float* __restrict__ h, const float* __restrict__ wn,
                  const int* __restrict__ starts, float* __restrict__ part) {
    int g = blockIdx.x, s = blockIdx.y, tid = threadIdx.x;
    int s0 = starts[g], s1 = starts[g + 1];
    float acc = 0.f;
    for (int n = s0 + s; n < s1; n += 4)
        acc += wn[n] * h[(size_t)n * HDIM + tid];
    part[((size_t)(g * 4 + s)) * HDIM + tid] = acc;
}
__global__ __launch_bounds__(256)
void pool_reduce(const float* __restrict__ part, float* __restrict__ pooled) {
    int g = blockIdx.x, tid = threadIdx.x;
    float s = 0.f;
    #pragma unroll
    for (int i = 0; i < 4; i++) s += part[((size_t)(g * 4 + i)) * HDIM + tid];
    pooled[g * HDIM + tid] = s;
}

__global__ __launch_bounds__(128)
void classify(const float* __restrict__ pooled, const float* __restrict__ w1,
              const float* __restrict__ b1, const float* __restrict__ w2,
              const float* __restrict__ b2, float* __restrict__ out) {
    int g = blockIdx.x;
    int tid = threadIdx.x;
    float acc = 0.f;
    for (int k = 0; k < HDIM; k++) acc += pooled[g * HDIM + k] * w1[k * 128 + tid];
    float t = fmaxf(acc + b1[tid], 0.f);
    float v = t * w2[tid];
    __shared__ float red[128];
    red[tid] = v; __syncthreads();
    for (int off = 64; off > 0; off >>= 1) {
        if (tid < off) red[tid] += red[tid + off];
        __syncthreads();
    }
    if (tid == 0) out[g] = red[0] + b2[0];
}

// ---------------------------------------------------------------------------
extern "C" void kernel_launch(void* const* d_in, const int* in_sizes, int n_in,
                              void* d_out, int out_size, void* d_ws, size_t ws_size,
                              hipStream_t stream) {
    const float* x      = (const float*)d_in[0];
    const int*   ei     = (const int*)  d_in[1];
    const int*   batch  = (const int*)  d_in[2];
    const float* proj_w = (const float*)d_in[3];
    const float* proj_b = (const float*)d_in[4];
    const float* conv_w = (const float*)d_in[5];
    const float* w_ih   = (const float*)d_in[6];
    const float* w_hh   = (const float*)d_in[7];
    const float* b_ih   = (const float*)d_in[8];
    const float* b_hh   = (const float*)d_in[9];
    const float* att_w1 = (const float*)d_in[10];
    const float* att_b1 = (const float*)d_in[11];
    const float* att_w2 = (const float*)d_in[12];
    const float* att_b2 = (const float*)d_in[13];
    const float* cls_w1 = (const float*)d_in[14];
    const float* cls_b1 = (const float*)d_in[15];
    const float* cls_w2 = (const float*)d_in[16];
    const float* cls_b2 = (const float*)d_in[17];
    float* out = (float*)d_out;

    char* ws = (char*)d_ws;
    size_t off = 0;
    auto alloc = [&](size_t bytes) -> void* {
        void* p = ws + off;
        off = (off + bytes + 255) & ~(size_t)255;
        return p;
    };
    // persistent
    float*          hf0    = (float*)         alloc((size_t)M_PAD * HDIM * 4);
    unsigned short* hb0    = (unsigned short*)alloc((size_t)M_PAD * HDIM * 2);
    unsigned short* hb1    = (unsigned short*)alloc((size_t)M_PAD * HDIM * 2);
    unsigned short* wihb   = (unsigned short*)alloc((size_t)3 * HDIM * HDIM * 2);
    unsigned short* whhb   = (unsigned short*)alloc((size_t)3 * HDIM * HDIM * 2);
    unsigned short* projWT = (unsigned short*)alloc((size_t)HDIM * KP * 2);
    unsigned short* convT  = (unsigned short*)alloc((size_t)L_LAYERS * HDIM * HDIM * 2);
    int*   rowptr = (int*)  alloc((N_NODES + 1) * 4);
    int*   cursor = (int*)  alloc((N_NODES + 1) * 4);
    int*   deg    = (int*)  alloc(N_NODES * 4);
    int*   csrc   = (int*)  alloc(N_EDGES * 4);
    float* scores = (float*)alloc(N_NODES * 4);
    int*   starts = (int*)  alloc((N_GRAPHS + 1) * 4);
    float* gmax   = (float*)alloc(N_GRAPHS * 4);
    float* gden   = (float*)alloc(N_GRAPHS * 4);
    float* wnode  = (float*)alloc(N_NODES * 4);
    float* ppart  = (float*)alloc((size_t)N_GRAPHS * 4 * HDIM * 4);
    float* pooled = (float*)alloc((size_t)N_GRAPHS * HDIM * 4);
    // union region: xb (proj phase) overlaps {mb, aggb, hf1} (layer phase)
    char* U = (char*)alloc((size_t)M_PAD * KP * 2 > (size_t)M_PAD * HDIM * (2 + 2 + 4)
                               ? (size_t)M_PAD * KP * 2
                               : (size_t)M_PAD * HDIM * (2 + 2 + 4));
    unsigned short* xb   = (unsigned short*)U;
    unsigned short* mb   = (unsigned short*)U;
    unsigned short* aggb = (unsigned short*)(U + (size_t)M_PAD * HDIM * 2);
    float*          hf1  = (float*)         (U + (size_t)M_PAD * HDIM * 4);
    (void)ws_size; (void)in_sizes; (void)n_in; (void)out_size;

    // ---- one-time prep ----
    prep_x     <<<dim3((N_NODES * KP) / 256), dim3(256), 0, stream>>>(x, xb);
    prep_projw <<<dim3((HDIM * KP) / 256), dim3(256), 0, stream>>>(proj_w, projWT);
    prep_convw <<<dim3((L_LAYERS * HDIM * HDIM) / 256), dim3(256), 0, stream>>>(conv_w, convT);
    prep_cast2 <<<dim3((3 * HDIM * HDIM) / 256), dim3(256), 0, stream>>>(
        w_ih, w_hh, wihb, whhb, 3 * HDIM * HDIM);

    // ---- input projection (+bias+relu) -> hf0 (f32) + hb0 (bf16) ----
    mm128<1><<<dim3(M_PAD / 128, 2), dim3(256), 0, stream>>>(
        xb, KP, projWT, KP, proj_b, hf0, hb0, KP / 32);

    // ---- CSR by dst ----
    hipMemsetAsync(deg, 0, N_NODES * 4, stream);
    edge_count<<<dim3((N_EDGES + 255) / 256), dim3(256), 0, stream>>>(ei, deg, N_EDGES);
    scan_rowptr<<<dim3(1), dim3(1024), 0, stream>>>(deg, rowptr, N_NODES);
    hipMemcpyAsync(cursor, rowptr, (N_NODES + 1) * 4, hipMemcpyDeviceToDevice, stream);
    edge_bucket<<<dim3((N_EDGES + 255) / 256), dim3(256), 0, stream>>>(ei, cursor, csrc, N_EDGES);
    seg_starts<<<dim3((N_NODES + 256) / 256), dim3(256), 0, stream>>>(batch, starts,
                                                                      N_NODES, N_GRAPHS);

    // ---- 5 message-passing layers ----
    float*          hfc = hf0;  float*          hfn = hf1;
    unsigned short* hbc = hb0;  unsigned short* hbn = hb1;
    for (int l = 0; l < L_LAYERS; l++) {
        mm128<0><<<dim3(M_PAD / 128, 2), dim3(256), 0, stream>>>(
            hbc, HDIM, convT + (size_t)l * HDIM * HDIM, HDIM, nullptr, nullptr, mb, HDIM / 32);
        agg_bf16<<<dim3((N_NODES * 64) / 256), dim3(256), 0, stream>>>(
            mb, rowptr, csrc, aggb, N_NODES);
        gru_mfma<<<dim3(M_PAD / 128, 4), dim3(512), 0, stream>>>(
            aggb, hbc, hfc, wihb, whhb, b_ih, b_hh, hfn, hbn);
        float* tf = hfc; hfc = hfn; hfn = tf;
        unsigned short* tb = hbc; hbc = hbn; hbn = tb;
    }

    // ---- attention pooling + classifier (fp32 on final h) ----
    att_scores2<<<dim3((N_NODES + 63) / 64), dim3(256), 0, stream>>>(
        hfc, att_w1, att_b1, att_w2, att_b2, scores);
    seg_stats<<<dim3((N_GRAPHS * 64 + 255) / 256), dim3(256), 0, stream>>>(
        scores, starts, gmax, gden);
    node_weights<<<dim3((N_NODES + 255) / 256), dim3(256), 0, stream>>>(
        scores, batch, gmax, gden, wnode);
    pool_partial<<<dim3(N_GRAPHS, 4), dim3(256), 0, stream>>>(hfc, wnode, starts, ppart);
    pool_reduce<<<dim3(N_GRAPHS), dim3(256), 0, stream>>>(ppart, pooled);
    classify<<<dim3(N_GRAPHS), dim3(128), 0, stream>>>(pooled, cls_w1, cls_b1,
                                                       cls_w2, cls_b2, out);
}

// Round 4
// 686.282 us; speedup vs baseline: 3.6340x; 1.0756x over previous
//
#include <hip/hip_runtime.h>
#include <hip/hip_bf16.h>
#include <math.h>

#define N_NODES 20000
#define M_PAD   20096          // 157*128; all row-dim ws buffers padded to this
#define N_EDGES 320000
#define N_GRAPHS 64
#define D_IN 771
#define KP   800               // padded K for projection (multiple of 32)
#define HDIM 256
#define L_LAYERS 5

typedef __attribute__((ext_vector_type(8))) short  bf16x8;
typedef __attribute__((ext_vector_type(4))) float  f32x4;

typedef __attribute__((address_space(3))) void       lds_void;
typedef __attribute__((address_space(1))) const void gconst_void;

__device__ __forceinline__ void gload16(const void* g, void* l) {
    __builtin_amdgcn_global_load_lds((gconst_void*)g, (lds_void*)l, 16, 0, 0);
}

__device__ __forceinline__ unsigned short f2bf(float f) {
    unsigned int u = __float_as_uint(f);
    return (unsigned short)((u + 0x7FFFu + ((u >> 16) & 1u)) >> 16);  // RNE
}
__device__ __forceinline__ float bf2f(unsigned short h) {
    return __uint_as_float(((unsigned int)h) << 16);
}

// swizzle: 16B slot XOR x(r), x(r)=(r>>1)&3  ->  2-way (free) bank aliasing
__device__ __forceinline__ int swz_src_elems(int lane, int lr) {
    return ((((lane & 3) * 16) ^ (((lr >> 1) & 3) << 4)) >> 1);
}
__device__ __forceinline__ int swz_read_bytes(int lane, int r) {
    return (((lane >> 4) * 16) ^ (((r >> 1) & 3) << 4));
}

// ---------------- prep kernels (bf16 casts / transposes, one-time) ----------
__global__ void prep_x(const float* __restrict__ x, unsigned short* __restrict__ xb) {
    size_t i = (size_t)blockIdx.x * 256 + threadIdx.x;     // over 20000*800
    if (i >= (size_t)N_NODES * KP) return;
    int r = (int)(i / KP), k = (int)(i % KP);
    float v = (k < D_IN) ? x[(size_t)r * D_IN + k] : 0.f;
    xb[i] = f2bf(v);
}
__global__ void prep_projw(const float* __restrict__ w, unsigned short* __restrict__ wt) {
    int i = blockIdx.x * 256 + threadIdx.x;                // over 256*800, wt[n][k]
    if (i >= HDIM * KP) return;
    int n = i / KP, k = i % KP;
    wt[i] = f2bf(k < D_IN ? w[(size_t)k * HDIM + n] : 0.f);
}
__global__ void prep_convw(const float* __restrict__ w, unsigned short* __restrict__ wt) {
    int i = blockIdx.x * 256 + threadIdx.x;                // over 5*256*256, wt[l][n][k]
    if (i >= L_LAYERS * HDIM * HDIM) return;
    int l = i / (HDIM * HDIM), rem = i % (HDIM * HDIM);
    int n = rem / HDIM, k = rem % HDIM;
    wt[i] = f2bf(w[(size_t)l * HDIM * HDIM + (size_t)k * HDIM + n]);
}
__global__ void prep_cast2(const float* __restrict__ a, const float* __restrict__ b,
                           unsigned short* __restrict__ ab, unsigned short* __restrict__ bb,
                           int n) {
    int i = blockIdx.x * 256 + threadIdx.x;
    if (i < n) { ab[i] = f2bf(a[i]); bb[i] = f2bf(b[i]); }
}

// ---------------- generic bf16 MFMA GEMM: C[M,256] = A[M,K] @ Bt[N,K]^T -----
// 128x128 tile, 4 waves (2x2), wave tile 64x64. 2-phase double-buffered LDS.
template<int EPI>   // 0: store Cb only; 1: bias+relu, store Cf and Cb
__global__ __launch_bounds__(256)
void mm128(const unsigned short* __restrict__ A, int lda,
           const unsigned short* __restrict__ Bt, int ldb,
           const float* __restrict__ bias,
           float* __restrict__ Cf, unsigned short* __restrict__ Cb, int nk) {
    __shared__ char lds[32768];                 // 2 x (8KB A + 8KB B)
    const int tid = threadIdx.x;
    const int lane = tid & 63, wave = tid >> 6;
    const int wm = wave >> 1, wn = wave & 1;
    const int row0 = blockIdx.x * 128, col0 = blockIdx.y * 128;
    const int lr = lane >> 2;
    const int kle = swz_src_elems(lane, lr);

    // per-wave staging sources (A chunks 2w,2w+1; B chunks 2w,2w+1)
    const unsigned short* sA[2];
    const unsigned short* sB[2];
    #pragma unroll
    for (int j = 0; j < 2; ++j) {
        int c = wave * 2 + j;
        sA[j] = A  + (size_t)(row0 + c * 16 + lr) * lda + kle;
        sB[j] = Bt + (size_t)(col0 + c * 16 + lr) * ldb + kle;
    }

    f32x4 acc[4][4];
    #pragma unroll
    for (int i = 0; i < 4; i++)
        #pragma unroll
        for (int j = 0; j < 4; j++) acc[i][j] = (f32x4){0.f, 0.f, 0.f, 0.f};

    auto stage = [&](int buf, int ks) {
        #pragma unroll
        for (int j = 0; j < 2; ++j) {
            int c = wave * 2 + j;
            gload16(sA[j] + ks * 32, lds + buf * 16384 + c * 1024);
            gload16(sB[j] + ks * 32, lds + buf * 16384 + 8192 + c * 1024);
        }
    };

    stage(0, 0);
    __syncthreads();
    for (int ks = 0; ks < nk; ++ks) {
        const int cur = ks & 1;
        if (ks + 1 < nk) stage(cur ^ 1, ks + 1);
        char* L = lds + cur * 16384;
        bf16x8 af[4], bfr[4];
        #pragma unroll
        for (int f = 0; f < 4; ++f) {
            int r = wm * 64 + f * 16 + (lane & 15);
            af[f] = *(const bf16x8*)(L + r * 64 + swz_read_bytes(lane, r));
            int cb = wn * 64 + f * 16 + (lane & 15);
            bfr[f] = *(const bf16x8*)(L + 8192 + cb * 64 + swz_read_bytes(lane, cb));
        }
        #pragma unroll
        for (int i = 0; i < 4; i++)
            #pragma unroll
            for (int j = 0; j < 4; j++)
                acc[i][j] = __builtin_amdgcn_mfma_f32_16x16x32_bf16(af[i], bfr[j], acc[i][j], 0, 0, 0);
        if (ks + 1 < nk) __syncthreads();
    }
    #pragma unroll
    for (int i = 0; i < 4; i++) {
        #pragma unroll
        for (int j = 0; j < 4; j++) {
            int cc = col0 + wn * 64 + j * 16 + (lane & 15);
            #pragma unroll
            for (int ri = 0; ri < 4; ++ri) {
                int rr = row0 + wm * 64 + i * 16 + (lane >> 4) * 4 + ri;
                float v = acc[i][j][ri];
                if (EPI == 1) { v += bias[cc]; v = fmaxf(v, 0.f); }
                if (EPI == 1) Cf[(size_t)rr * HDIM + cc] = v;
                Cb[(size_t)rr * HDIM + cc] = f2bf(v);
            }
        }
    }
}

// ---------------- fused GRU: 128x64 tile, 8 waves (4x2), 2-phase dbuf -------
// 6 GEMM sets (gi/gh x r,z,n); wave tile 32x32 per set.
// LDS per buf: Aagg[128][64B]@0, Ah@8192, 6x B[64][64B]@16384+t*4096 = 40KB.
__global__ __launch_bounds__(512)
void gru_mfma(const unsigned short* __restrict__ aggb, const unsigned short* __restrict__ hb,
              const float* __restrict__ hf,
              const unsigned short* __restrict__ wih, const unsigned short* __restrict__ whh,
              const float* __restrict__ bih, const float* __restrict__ bhh,
              float* __restrict__ hfN, unsigned short* __restrict__ hbN) {
    __shared__ char lds[81920];                 // 2 x 40KB
    const int tid = threadIdx.x;
    const int lane = tid & 63, wave = tid >> 6;   // 8 waves
    const int wm = wave >> 1, wn = wave & 1;      // 4 x 2
    const int row0 = blockIdx.x * 128, col0 = blockIdx.y * 64;
    const int lr = lane >> 2;
    const int kle = swz_src_elems(lane, lr);

    // per-wave staging sources: 5 chunks (8 Aagg, 8 Ah, 24 B across 8 waves)
    const unsigned short* srcs[5];
    #pragma unroll
    for (int j = 0; j < 5; ++j) {
        int c = wave + j * 8;
        const unsigned short* src;
        if (c < 8)       src = aggb + (size_t)(row0 + c * 16 + lr) * HDIM;
        else if (c < 16) src = hb   + (size_t)(row0 + (c - 8) * 16 + lr) * HDIM;
        else {
            int t = (c - 16) >> 2, c4 = (c - 16) & 3;
            int s = t >> 1;
            const unsigned short* W = (t & 1) ? whh : wih;
            src = W + (size_t)(s * HDIM + col0 + c4 * 16 + lr) * HDIM;
        }
        srcs[j] = src + kle;
    }

    f32x4 acc[3][2][2][2];
    #pragma unroll
    for (int s = 0; s < 3; s++)
        #pragma unroll
        for (int m = 0; m < 2; m++)
            #pragma unroll
            for (int i = 0; i < 2; i++)
                #pragma unroll
                for (int j = 0; j < 2; j++) acc[s][m][i][j] = (f32x4){0.f, 0.f, 0.f, 0.f};

    auto stage = [&](int buf, int ks) {
        #pragma unroll
        for (int j = 0; j < 5; ++j) {
            int c = wave + j * 8;
            gload16(srcs[j] + ks * 32, lds + buf * 40960 + c * 1024);
        }
    };

    stage(0, 0);
    __syncthreads();
    for (int ks = 0; ks < 8; ++ks) {
        const int cur = ks & 1;
        if (ks < 7) stage(cur ^ 1, ks + 1);
        char* L = lds + cur * 40960;
        bf16x8 a[2][2];
        #pragma unroll
        for (int m = 0; m < 2; m++)
            #pragma unroll
            for (int fr = 0; fr < 2; fr++) {
                int r = wm * 32 + fr * 16 + (lane & 15);
                a[m][fr] = *(const bf16x8*)(L + m * 8192 + r * 64 + swz_read_bytes(lane, r));
            }
        #pragma unroll
        for (int s = 0; s < 3; s++) {
            bf16x8 b[2][2];
            #pragma unroll
            for (int m = 0; m < 2; m++)
                #pragma unroll
                for (int fc = 0; fc < 2; fc++) {
                    int rb = wn * 32 + fc * 16 + (lane & 15);
                    b[m][fc] = *(const bf16x8*)(L + 16384 + (s * 2 + m) * 4096 + rb * 64 +
                                                swz_read_bytes(lane, rb));
                }
            #pragma unroll
            for (int m = 0; m < 2; m++)
                #pragma unroll
                for (int fr = 0; fr < 2; fr++)
                    #pragma unroll
                    for (int fc = 0; fc < 2; fc++)
                        acc[s][m][fr][fc] = __builtin_amdgcn_mfma_f32_16x16x32_bf16(
                            a[m][fr], b[m][fc], acc[s][m][fr][fc], 0, 0, 0);
        }
        if (ks < 7) __syncthreads();
    }
    #pragma unroll
    for (int fr = 0; fr < 2; fr++)
        #pragma unroll
        for (int fc = 0; fc < 2; fc++) {
            int cc = col0 + wn * 32 + fc * 16 + (lane & 15);
            float bir = bih[cc],            bhr = bhh[cc];
            float biz = bih[HDIM + cc],     bhz = bhh[HDIM + cc];
            float bin = bih[2 * HDIM + cc], bhn = bhh[2 * HDIM + cc];
            #pragma unroll
            for (int ri = 0; ri < 4; ++ri) {
                int rr = row0 + wm * 32 + fr * 16 + (lane >> 4) * 4 + ri;
                float xr = acc[0][0][fr][fc][ri] + bir + acc[0][1][fr][fc][ri] + bhr;
                float xz = acc[1][0][fr][fc][ri] + biz + acc[1][1][fr][fc][ri] + bhz;
                float gn = acc[2][0][fr][fc][ri] + bin;
                float hn = acc[2][1][fr][fc][ri] + bhn;
                float r_ = 1.f / (1.f + expf(-xr));
                float z_ = 1.f / (1.f + expf(-xz));
                float n_ = tanhf(gn + r_ * hn);
                float ho = hf[(size_t)rr * HDIM + cc];
                float v  = (1.f - z_) * n_ + z_ * ho;
                hfN[(size_t)rr * HDIM + cc] = v;
                hbN[(size_t)rr * HDIM + cc] = f2bf(v);
            }
        }
}

// -------------------------- CSR build ---------------------------------------
__global__ void edge_count(const int* __restrict__ ei, int* __restrict__ deg, int E) {
    int e = blockIdx.x * 256 + threadIdx.x;
    if (e < E) atomicAdd(&deg[ei[E + e]], 1);
}
__global__ __launch_bounds__(1024)
void scan_rowptr(const int* __restrict__ deg, int* __restrict__ rowptr, int N) {
    __shared__ int bs[1024];
    const int tid = threadIdx.x;
    const int CH = (N + 1023) / 1024;
    const int base = tid * CH;
    int sum = 0;
    for (int i = 0; i < CH; i++) { int idx = base + i; sum += (idx < N) ? deg[idx] : 0; }
    bs[tid] = sum; __syncthreads();
    for (int off = 1; off < 1024; off <<= 1) {
        int v = (tid >= off) ? bs[tid - off] : 0;
        __syncthreads();
        bs[tid] += v;
        __syncthreads();
    }
    int run = (tid > 0) ? bs[tid - 1] : 0;
    for (int i = 0; i < CH; i++) {
        int idx = base + i;
        if (idx < N) { rowptr[idx] = run; run += deg[idx]; }
    }
    if (tid == 0) rowptr[N] = bs[1023];
}
__global__ void edge_bucket(const int* __restrict__ ei, int* __restrict__ cursor,
                            int* __restrict__ csrc, int E) {
    int e = blockIdx.x * 256 + threadIdx.x;
    if (e < E) {
        int d = ei[E + e];
        int p = atomicAdd(&cursor[d], 1);
        csrc[p] = ei[e];
    }
}

// one wave per node, bf16 m rows (512B each): agg = sum of in-edge m[src]
__global__ __launch_bounds__(256)
void agg_bf16(const unsigned short* __restrict__ m, const int* __restrict__ rowptr,
              const int* __restrict__ csrc, unsigned short* __restrict__ agg, int N) {
    int wv = (blockIdx.x * 256 + threadIdx.x) >> 6;
    int lane = threadIdx.x & 63;
    if (wv >= N) return;
    int s0 = rowptr[wv], s1 = rowptr[wv + 1];
    float a0 = 0.f, a1 = 0.f, a2 = 0.f, a3 = 0.f;
    for (int e = s0; e < s1; e++) {
        const unsigned short* r = m + (size_t)csrc[e] * HDIM + lane * 4;
        ushort4 v = *(const ushort4*)r;
        a0 += bf2f(v.x); a1 += bf2f(v.y); a2 += bf2f(v.z); a3 += bf2f(v.w);
    }
    ushort4 o = { f2bf(a0), f2bf(a1), f2bf(a2), f2bf(a3) };
    *(ushort4*)(agg + (size_t)wv * HDIM + lane * 4) = o;
}

// -------------------------- attention + head --------------------------------
__global__ void seg_starts(const int* __restrict__ batch, int* __restrict__ starts,
                           int N, int G) {
    int n = blockIdx.x * 256 + threadIdx.x;
    if (n > N) return;
    int b  = (n < N) ? batch[n] : G;
    int bp = (n == 0) ? -1 : batch[n - 1];
    for (int g = bp + 1; g <= b; g++) starts[g] = n;
}

// fused fp32 GEMM scores: 64 rows x 128 cols per block, tanh*w2 + row-reduce.
__global__ __launch_bounds__(256)
void att_scores2(const float* __restrict__ h, const float* __restrict__ w1,
                 const float* __restrict__ b1, const float* __restrict__ w2,
                 const float* __restrict__ b2, float* __restrict__ scores) {
    __shared__ float As[16][68];
    __shared__ float Bs[16][136];
    __shared__ float red[64][17];
    const int tid = threadIdx.x;
    const int row0 = blockIdx.x * 64;
    const int tm = (tid & 15) * 4, tn = (tid >> 4) * 8;
    const int ar = tid >> 2, ac = (tid & 3) * 4;
    const int br = tid >> 4, bc = (tid & 15) * 8;
    float acc[4][8] = {};
    for (int k0 = 0; k0 < HDIM; k0 += 16) {
        float4 av = {0.f, 0.f, 0.f, 0.f};
        int arow = row0 + ar;
        if (arow < N_NODES) av = *(const float4*)(h + (size_t)arow * HDIM + k0 + ac);
        As[ac + 0][ar] = av.x; As[ac + 1][ar] = av.y;
        As[ac + 2][ar] = av.z; As[ac + 3][ar] = av.w;
        *(float4*)&Bs[br][bc]     = *(const float4*)(w1 + (size_t)(k0 + br) * 128 + bc);
        *(float4*)&Bs[br][bc + 4] = *(const float4*)(w1 + (size_t)(k0 + br) * 128 + bc + 4);
        __syncthreads();
        #pragma unroll
        for (int kk = 0; kk < 16; kk++) {
            float4 a4 = *(const float4*)&As[kk][tm];
            float4 b4 = *(const float4*)&Bs[kk][tn];
            float4 c4 = *(const float4*)&Bs[kk][tn + 4];
            float aa[4] = {a4.x, a4.y, a4.z, a4.w};
            float bb[8] = {b4.x, b4.y, b4.z, b4.w, c4.x, c4.y, c4.z, c4.w};
            #pragma unroll
            for (int i = 0; i < 4; i++)
                #pragma unroll
                for (int j = 0; j < 8; j++) acc[i][j] += aa[i] * bb[j];
        }
        __syncthreads();
    }
    #pragma unroll
    for (int i = 0; i < 4; i++) {
        float s = 0.f;
        #pragma unroll
        for (int j = 0; j < 8; j++)
            s += tanhf(acc[i][j] + b1[tn + j]) * w2[tn + j];
        red[tm + i][tid >> 4] = s;
    }
    __syncthreads();
    if (tid < 64) {
        float s = 0.f;
        #pragma unroll
        for (int g = 0; g < 16; g++) s += red[tid][g];
        int n = row0 + tid;
        if (n < N_NODES) scores[n] = s + b2[0];
    }
}

// per-graph max + denom: one wave per graph
__global__ __launch_bounds__(256)
void seg_stats(const float* __restrict__ scores, const int* __restrict__ starts,
               float* __restrict__ gmax, float* __restrict__ gden) {
    int wv = (blockIdx.x * 256 + threadIdx.x) >> 6;
    int lane = threadIdx.x & 63;
    if (wv >= N_GRAPHS) return;
    int s0 = starts[wv], s1 = starts[wv + 1];
    float mx = -1e30f;
    for (int n = s0 + lane; n < s1; n += 64) mx = fmaxf(mx, scores[n]);
    #pragma unroll
    for (int off = 32; off > 0; off >>= 1) mx = fmaxf(mx, __shfl_xor(mx, off));
    float se = 0.f;
    for (int n = s0 + lane; n < s1; n += 64) se += expf(scores[n] - mx);
    #pragma unroll
    for (int off = 32; off > 0; off >>= 1) se += __shfl_xor(se, off);
    if (lane == 0) { gmax[wv] = mx; gden[wv] = se; }
}

__global__ void node_weights(const float* __restrict__ scores, const int* __restrict__ batch,
                             const float* __restrict__ gmax, const float* __restrict__ gden,
                             float* __restrict__ wn) {
    int n = blockIdx.x * 256 + threadIdx.x;
    if (n >= N_NODES) return;
    int g = batch[n];
    float d = gden[g];
    wn[n] = (d > 0.f) ? expf(scores[n] - gmax[g]) / d : 0.f;
}

// deterministic 4-stripe weighted pool: block (g,s) handles nodes n≡s (mod 4)
__global__ __launch_bounds__(256)
void pool_partial(const float* __restrict__ h, const float* __restrict__ wn,
                  const int* __restrict__ starts, float* __restrict__ part) {
    int g = blockIdx.x, s = blockIdx.y, tid = threadIdx.x;
    int s0 = starts[g], s1 = starts[g + 1];
    float acc = 0.f;
    for (int n = s0 + s; n < s1; n += 4)
        acc += wn[n] * h[(size_t)n * HDIM + tid];
    part[((size_t)(g * 4 + s)) * HDIM + tid] = acc;
}
__global__ __launch_bounds__(256)
void pool_reduce(const float* __restrict__ part, float* __restrict__ pooled) {
    int g = blockIdx.x, tid = threadIdx.x;
    float s = 0.f;
    #pragma unroll
    for (int i = 0; i < 4; i++) s += part[((size_t)(g * 4 + i)) * HDIM + tid];
    pooled[g * HDIM + tid] = s;
}

__global__ __launch_bounds__(128)
void classify(const float* __restrict__ pooled, const float* __restrict__ w1,
              const float* __restrict__ b1, const float* __restrict__ w2,
              const float* __restrict__ b2, float* __restrict__ out) {
    int g = blockIdx.x;
    int tid = threadIdx.x;
    float acc = 0.f;
    for (int k = 0; k < HDIM; k++) acc += pooled[g * HDIM + k] * w1[k * 128 + tid];
    float t = fmaxf(acc + b1[tid], 0.f);
    float v = t * w2[tid];
    __shared__ float red[128];
    red[tid] = v; __syncthreads();
    for (int off = 64; off > 0; off >>= 1) {
        if (tid < off) red[tid] += red[tid + off];
        __syncthreads();
    }
    if (tid == 0) out[g] = red[0] + b2[0];
}

// ---------------------------------------------------------------------------
extern "C" void kernel_launch(void* const* d_in, const int* in_sizes, int n_in,
                              void* d_out, int out_size, void* d_ws, size_t ws_size,
                              hipStream_t stream) {
    const float* x      = (const float*)d_in[0];
    const int*   ei     = (const int*)  d_in[1];
    const int*   batch  = (const int*)  d_in[2];
    const float* proj_w = (const float*)d_in[3];
    const float* proj_b = (const float*)d_in[4];
    const float* conv_w = (const float*)d_in[5];
    const float* w_ih   = (const float*)d_in[6];
    const float* w_hh   = (const float*)d_in[7];
    const float* b_ih   = (const float*)d_in[8];
    const float* b_hh   = (const float*)d_in[9];
    const float* att_w1 = (const float*)d_in[10];
    const float* att_b1 = (const float*)d_in[11];
    const float* att_w2 = (const float*)d_in[12];
    const float* att_b2 = (const float*)d_in[13];
    const float* cls_w1 = (const float*)d_in[14];
    const float* cls_b1 = (const float*)d_in[15];
    const float* cls_w2 = (const float*)d_in[16];
    const float* cls_b2 = (const float*)d_in[17];
    float* out = (float*)d_out;

    char* ws = (char*)d_ws;
    size_t off = 0;
    auto alloc = [&](size_t bytes) -> void* {
        void* p = ws + off;
        off = (off + bytes + 255) & ~(size_t)255;
        return p;
    };
    // persistent
    float*          hf0    = (float*)         alloc((size_t)M_PAD * HDIM * 4);
    unsigned short* hb0    = (unsigned short*)alloc((size_t)M_PAD * HDIM * 2);
    unsigned short* hb1    = (unsigned short*)alloc((size_t)M_PAD * HDIM * 2);
    unsigned short* wihb   = (unsigned short*)alloc((size_t)3 * HDIM * HDIM * 2);
    unsigned short* whhb   = (unsigned short*)alloc((size_t)3 * HDIM * HDIM * 2);
    unsigned short* projWT = (unsigned short*)alloc((size_t)HDIM * KP * 2);
    unsigned short* convT  = (unsigned short*)alloc((size_t)L_LAYERS * HDIM * HDIM * 2);
    int*   rowptr = (int*)  alloc((N_NODES + 1) * 4);
    int*   cursor = (int*)  alloc((N_NODES + 1) * 4);
    int*   deg    = (int*)  alloc(N_NODES * 4);
    int*   csrc   = (int*)  alloc(N_EDGES * 4);
    float* scores = (float*)alloc(N_NODES * 4);
    int*   starts = (int*)  alloc((N_GRAPHS + 1) * 4);
    float* gmax   = (float*)alloc(N_GRAPHS * 4);
    float* gden   = (float*)alloc(N_GRAPHS * 4);
    float* wnode  = (float*)alloc(N_NODES * 4);
    float* ppart  = (float*)alloc((size_t)N_GRAPHS * 4 * HDIM * 4);
    float* pooled = (float*)alloc((size_t)N_GRAPHS * HDIM * 4);
    // union region: xb (proj phase) overlaps {mb, aggb, hf1} (layer phase)
    char* U = (char*)alloc((size_t)M_PAD * KP * 2 > (size_t)M_PAD * HDIM * (2 + 2 + 4)
                               ? (size_t)M_PAD * KP * 2
                               : (size_t)M_PAD * HDIM * (2 + 2 + 4));
    unsigned short* xb   = (unsigned short*)U;
    unsigned short* mb   = (unsigned short*)U;
    unsigned short* aggb = (unsigned short*)(U + (size_t)M_PAD * HDIM * 2);
    float*          hf1  = (float*)         (U + (size_t)M_PAD * HDIM * 4);
    (void)ws_size; (void)in_sizes; (void)n_in; (void)out_size;

    // ---- one-time prep ----
    prep_x     <<<dim3((N_NODES * KP) / 256), dim3(256), 0, stream>>>(x, xb);
    prep_projw <<<dim3((HDIM * KP) / 256), dim3(256), 0, stream>>>(proj_w, projWT);
    prep_convw <<<dim3((L_LAYERS * HDIM * HDIM) / 256), dim3(256), 0, stream>>>(conv_w, convT);
    prep_cast2 <<<dim3((3 * HDIM * HDIM) / 256), dim3(256), 0, stream>>>(
        w_ih, w_hh, wihb, whhb, 3 * HDIM * HDIM);

    // ---- input projection (+bias+relu) -> hf0 (f32) + hb0 (bf16) ----
    mm128<1><<<dim3(M_PAD / 128, 2), dim3(256), 0, stream>>>(
        xb, KP, projWT, KP, proj_b, hf0, hb0, KP / 32);

    // ---- CSR by dst ----
    hipMemsetAsync(deg, 0, N_NODES * 4, stream);
    edge_count<<<dim3((N_EDGES + 255) / 256), dim3(256), 0, stream>>>(ei, deg, N_EDGES);
    scan_rowptr<<<dim3(1), dim3(1024), 0, stream>>>(deg, rowptr, N_NODES);
    hipMemcpyAsync(cursor, rowptr, (N_NODES + 1) * 4, hipMemcpyDeviceToDevice, stream);
    edge_bucket<<<dim3((N_EDGES + 255) / 256), dim3(256), 0, stream>>>(ei, cursor, csrc, N_EDGES);
    seg_starts<<<dim3((N_NODES + 256) / 256), dim3(256), 0, stream>>>(batch, starts,
                                                                      N_NODES, N_GRAPHS);

    // ---- 5 message-passing layers ----
    float*          hfc = hf0;  float*          hfn = hf1;
    unsigned short* hbc = hb0;  unsigned short* hbn = hb1;
    for (int l = 0; l < L_LAYERS; l++) {
        mm128<0><<<dim3(M_PAD / 128, 2), dim3(256), 0, stream>>>(
            hbc, HDIM, convT + (size_t)l * HDIM * HDIM, HDIM, nullptr, nullptr, mb, HDIM / 32);
        agg_bf16<<<dim3((N_NODES * 64) / 256), dim3(256), 0, stream>>>(
            mb, rowptr, csrc, aggb, N_NODES);
        gru_mfma<<<dim3(M_PAD / 128, 4), dim3(512), 0, stream>>>(
            aggb, hbc, hfc, wihb, whhb, b_ih, b_hh, hfn, hbn);
        float* tf = hfc; hfc = hfn; hfn = tf;
        unsigned short* tb = hbc; hbc = hbn; hbn = tb;
    }

    // ---- attention pooling + classifier (fp32 on final h) ----
    att_scores2<<<dim3((N_NODES + 63) / 64), dim3(256), 0, stream>>>(
        hfc, att_w1, att_b1, att_w2, att_b2, scores);
    seg_stats<<<dim3((N_GRAPHS * 64 + 255) / 256), dim3(256), 0, stream>>>(
        scores, starts, gmax, gden);
    node_weights<<<dim3((N_NODES + 255) / 256), dim3(256), 0, stream>>>(
        scores, batch, gmax, gden, wnode);
    pool_partial<<<dim3(N_GRAPHS, 4), dim3(256), 0, stream>>>(hfc, wnode, starts, ppart);
    pool_reduce<<<dim3(N_GRAPHS), dim3(256), 0, stream>>>(ppart, pooled);
    classify<<<dim3(N_GRAPHS), dim3(128), 0, stream>>>(pooled, cls_w1, cls_b1,
                                                       cls_w2, cls_b2, out);
}

// Round 5
// 645.554 us; speedup vs baseline: 3.8633x; 1.0631x over previous
//
#include <hip/hip_runtime.h>
#include <hip/hip_bf16.h>
#include <math.h>

#define N_NODES 20000
#define M_PAD   20096          // 157*128; all row-dim ws buffers padded to this
#define N_EDGES 320000
#define N_GRAPHS 64
#define D_IN 771
#define KP   800               // padded K for projection (multiple of 32)
#define HDIM 256
#define L_LAYERS 5

typedef __attribute__((ext_vector_type(8))) short  bf16x8;
typedef __attribute__((ext_vector_type(4))) float  f32x4;

typedef __attribute__((address_space(3))) void       lds_void;
typedef __attribute__((address_space(1))) const void gconst_void;

__device__ __forceinline__ void gload16(const void* g, void* l) {
    __builtin_amdgcn_global_load_lds((gconst_void*)g, (lds_void*)l, 16, 0, 0);
}

__device__ __forceinline__ unsigned short f2bf(float f) {
    unsigned int u = __float_as_uint(f);
    return (unsigned short)((u + 0x7FFFu + ((u >> 16) & 1u)) >> 16);  // RNE
}
__device__ __forceinline__ float bf2f(unsigned short h) {
    return __uint_as_float(((unsigned int)h) << 16);
}

// swizzle: 16B slot XOR x(r), x(r)=(r>>1)&3  ->  2-way (free) bank aliasing
__device__ __forceinline__ int swz_src_elems(int lane, int lr) {
    return ((((lane & 3) * 16) ^ (((lr >> 1) & 3) << 4)) >> 1);
}
__device__ __forceinline__ int swz_read_bytes(int lane, int r) {
    return (((lane >> 4) * 16) ^ (((r >> 1) & 3) << 4));
}

// ---------------- prep kernels (bf16 casts / transposes, one-time) ----------
__global__ void prep_x(const float* __restrict__ x, unsigned short* __restrict__ xb) {
    size_t i = (size_t)blockIdx.x * 256 + threadIdx.x;     // over 20000*800
    if (i >= (size_t)N_NODES * KP) return;
    int r = (int)(i / KP), k = (int)(i % KP);
    float v = (k < D_IN) ? x[(size_t)r * D_IN + k] : 0.f;
    xb[i] = f2bf(v);
}
__global__ void prep_projw(const float* __restrict__ w, unsigned short* __restrict__ wt) {
    int i = blockIdx.x * 256 + threadIdx.x;                // over 256*800, wt[n][k]
    if (i >= HDIM * KP) return;
    int n = i / KP, k = i % KP;
    wt[i] = f2bf(k < D_IN ? w[(size_t)k * HDIM + n] : 0.f);
}
__global__ void prep_convw(const float* __restrict__ w, unsigned short* __restrict__ wt) {
    int i = blockIdx.x * 256 + threadIdx.x;                // over 5*256*256, wt[l][n][k]
    if (i >= L_LAYERS * HDIM * HDIM) return;
    int l = i / (HDIM * HDIM), rem = i % (HDIM * HDIM);
    int n = rem / HDIM, k = rem % HDIM;
    wt[i] = f2bf(w[(size_t)l * HDIM * HDIM + (size_t)k * HDIM + n]);
}
__global__ void prep_cast2(const float* __restrict__ a, const float* __restrict__ b,
                           unsigned short* __restrict__ ab, unsigned short* __restrict__ bb,
                           int n) {
    int i = blockIdx.x * 256 + threadIdx.x;
    if (i < n) { ab[i] = f2bf(a[i]); bb[i] = f2bf(b[i]); }
}

// ---------------- generic bf16 MFMA GEMM: C[M,256] = A[M,K] @ Bt[N,K]^T -----
// 128x128 tile, 4 waves (2x2), wave tile 64x64. 2-phase double-buffered LDS.
template<int EPI>   // 0: store Cb only; 1: bias+relu, store Cf and Cb
__global__ __launch_bounds__(256)
void mm128(const unsigned short* __restrict__ A, int lda,
           const unsigned short* __restrict__ Bt, int ldb,
           const float* __restrict__ bias,
           float* __restrict__ Cf, unsigned short* __restrict__ Cb, int nk) {
    __shared__ char lds[32768];                 // 2 x (8KB A + 8KB B)
    const int tid = threadIdx.x;
    const int lane = tid & 63, wave = tid >> 6;
    const int wm = wave >> 1, wn = wave & 1;
    const int row0 = blockIdx.x * 128, col0 = blockIdx.y * 128;
    const int lr = lane >> 2;
    const int kle = swz_src_elems(lane, lr);

    // per-wave staging sources (A chunks 2w,2w+1; B chunks 2w,2w+1)
    const unsigned short* sA[2];
    const unsigned short* sB[2];
    #pragma unroll
    for (int j = 0; j < 2; ++j) {
        int c = wave * 2 + j;
        sA[j] = A  + (size_t)(row0 + c * 16 + lr) * lda + kle;
        sB[j] = Bt + (size_t)(col0 + c * 16 + lr) * ldb + kle;
    }

    f32x4 acc[4][4];
    #pragma unroll
    for (int i = 0; i < 4; i++)
        #pragma unroll
        for (int j = 0; j < 4; j++) acc[i][j] = (f32x4){0.f, 0.f, 0.f, 0.f};

    auto stage = [&](int buf, int ks) {
        #pragma unroll
        for (int j = 0; j < 2; ++j) {
            int c = wave * 2 + j;
            gload16(sA[j] + ks * 32, lds + buf * 16384 + c * 1024);
            gload16(sB[j] + ks * 32, lds + buf * 16384 + 8192 + c * 1024);
        }
    };

    stage(0, 0);
    __syncthreads();
    for (int ks = 0; ks < nk; ++ks) {
        const int cur = ks & 1;
        if (ks + 1 < nk) stage(cur ^ 1, ks + 1);
        char* L = lds + cur * 16384;
        bf16x8 af[4], bfr[4];
        #pragma unroll
        for (int f = 0; f < 4; ++f) {
            int r = wm * 64 + f * 16 + (lane & 15);
            af[f] = *(const bf16x8*)(L + r * 64 + swz_read_bytes(lane, r));
            int cb = wn * 64 + f * 16 + (lane & 15);
            bfr[f] = *(const bf16x8*)(L + 8192 + cb * 64 + swz_read_bytes(lane, cb));
        }
        #pragma unroll
        for (int i = 0; i < 4; i++)
            #pragma unroll
            for (int j = 0; j < 4; j++)
                acc[i][j] = __builtin_amdgcn_mfma_f32_16x16x32_bf16(af[i], bfr[j], acc[i][j], 0, 0, 0);
        if (ks + 1 < nk) __syncthreads();
    }
    #pragma unroll
    for (int i = 0; i < 4; i++) {
        #pragma unroll
        for (int j = 0; j < 4; j++) {
            int cc = col0 + wn * 64 + j * 16 + (lane & 15);
            #pragma unroll
            for (int ri = 0; ri < 4; ++ri) {
                int rr = row0 + wm * 64 + i * 16 + (lane >> 4) * 4 + ri;
                float v = acc[i][j][ri];
                if (EPI == 1) { v += bias[cc]; v = fmaxf(v, 0.f); }
                if (EPI == 1) Cf[(size_t)rr * HDIM + cc] = v;
                Cb[(size_t)rr * HDIM + cc] = f2bf(v);
            }
        }
    }
}

// ---------------- fused GRU v3: 64x64 tile, 4 waves (2x2), single buffer ----
// Small blocks + low VGPR => 3 blocks/CU co-resident (m114 implicit overlap).
// LDS: Aagg[64][64B]@0, Ah@4096, 6x B[64][64B]@8192+t*4096 = 32KB.
__global__ __launch_bounds__(256, 3)
void gru_mfma(const unsigned short* __restrict__ aggb, const unsigned short* __restrict__ hb,
              const float* __restrict__ hf,
              const unsigned short* __restrict__ wih, const unsigned short* __restrict__ whh,
              const float* __restrict__ bih, const float* __restrict__ bhh,
              float* __restrict__ hfN, unsigned short* __restrict__ hbN) {
    __shared__ char lds[32768];
    const int tid = threadIdx.x;
    const int lane = tid & 63, wave = tid >> 6;   // 4 waves
    const int wm = wave >> 1, wn = wave & 1;      // 2 x 2
    const int row0 = blockIdx.x * 64, col0 = blockIdx.y * 64;
    const int lr = lane >> 2;
    const int laneoff = lr * HDIM + swz_src_elems(lane, lr);  // per-lane elems

    f32x4 acc[3][2][2][2];
    #pragma unroll
    for (int s = 0; s < 3; s++)
        #pragma unroll
        for (int m = 0; m < 2; m++)
            #pragma unroll
            for (int i = 0; i < 2; i++)
                #pragma unroll
                for (int j = 0; j < 2; j++) acc[s][m][i][j] = (f32x4){0.f, 0.f, 0.f, 0.f};

    // stage: 32 chunks of 1KB, 8 per wave (c = wave*8+j).
    // c<4: agg rows; c<8: h rows; c>=8: weight slab t=(c-8)>>2, sub-chunk c4.
    auto stage = [&](int ks) {
        #pragma unroll
        for (int j = 0; j < 8; ++j) {
            int c = wave * 8 + j;
            const unsigned short* p;
            int uo;
            if (c < 4)      { p = aggb; uo = (row0 + c * 16) * HDIM; }
            else if (c < 8) { p = hb;   uo = (row0 + (c - 4) * 16) * HDIM; }
            else {
                int t = (c - 8) >> 2, c4 = (c - 8) & 3;
                int s = t >> 1;
                p = (t & 1) ? whh : wih;
                uo = (s * HDIM + col0 + c4 * 16) * HDIM;
            }
            uo = __builtin_amdgcn_readfirstlane(uo);   // force SGPR base
            gload16(p + uo + laneoff + ks * 32, lds + c * 1024);
        }
    };

    for (int ks = 0; ks < 8; ++ks) {
        stage(ks);
        __syncthreads();        // drains vmcnt -> LDS data visible
        bf16x8 a[2][2];
        #pragma unroll
        for (int m = 0; m < 2; m++)
            #pragma unroll
            for (int fr = 0; fr < 2; fr++) {
                int r = wm * 32 + fr * 16 + (lane & 15);
                a[m][fr] = *(const bf16x8*)(lds + m * 4096 + r * 64 + swz_read_bytes(lane, r));
            }
        #pragma unroll
        for (int s = 0; s < 3; s++) {
            bf16x8 b[2][2];
            #pragma unroll
            for (int m = 0; m < 2; m++)
                #pragma unroll
                for (int fc = 0; fc < 2; fc++) {
                    int rb = wn * 32 + fc * 16 + (lane & 15);
                    b[m][fc] = *(const bf16x8*)(lds + 8192 + (s * 2 + m) * 4096 + rb * 64 +
                                                swz_read_bytes(lane, rb));
                }
            #pragma unroll
            for (int m = 0; m < 2; m++)
                #pragma unroll
                for (int fr = 0; fr < 2; fr++)
                    #pragma unroll
                    for (int fc = 0; fc < 2; fc++)
                        acc[s][m][fr][fc] = __builtin_amdgcn_mfma_f32_16x16x32_bf16(
                            a[m][fr], b[m][fc], acc[s][m][fr][fc], 0, 0, 0);
        }
        if (ks < 7) __syncthreads();   // all reads done before next overwrite
    }
    #pragma unroll
    for (int fr = 0; fr < 2; fr++)
        #pragma unroll
        for (int fc = 0; fc < 2; fc++) {
            int cc = col0 + wn * 32 + fc * 16 + (lane & 15);
            float bir = bih[cc],            bhr = bhh[cc];
            float biz = bih[HDIM + cc],     bhz = bhh[HDIM + cc];
            float bin = bih[2 * HDIM + cc], bhn = bhh[2 * HDIM + cc];
            #pragma unroll
            for (int ri = 0; ri < 4; ++ri) {
                int rr = row0 + wm * 32 + fr * 16 + (lane >> 4) * 4 + ri;
                float xr = acc[0][0][fr][fc][ri] + bir + acc[0][1][fr][fc][ri] + bhr;
                float xz = acc[1][0][fr][fc][ri] + biz + acc[1][1][fr][fc][ri] + bhz;
                float gn = acc[2][0][fr][fc][ri] + bin;
                float hn = acc[2][1][fr][fc][ri] + bhn;
                float r_ = 1.f / (1.f + expf(-xr));
                float z_ = 1.f / (1.f + expf(-xz));
                float n_ = tanhf(gn + r_ * hn);
                float ho = hf[(size_t)rr * HDIM + cc];
                float v  = (1.f - z_) * n_ + z_ * ho;
                hfN[(size_t)rr * HDIM + cc] = v;
                hbN[(size_t)rr * HDIM + cc] = f2bf(v);
            }
        }
}

// -------------------------- CSR build ---------------------------------------
__global__ void edge_count(const int* __restrict__ ei, int* __restrict__ deg, int E) {
    int e = blockIdx.x * 256 + threadIdx.x;
    if (e < E) atomicAdd(&deg[ei[E + e]], 1);
}
__global__ __launch_bounds__(1024)
void scan_rowptr(const int* __restrict__ deg, int* __restrict__ rowptr, int N) {
    __shared__ int bs[1024];
    const int tid = threadIdx.x;
    const int CH = (N + 1023) / 1024;
    const int base = tid * CH;
    int sum = 0;
    for (int i = 0; i < CH; i++) { int idx = base + i; sum += (idx < N) ? deg[idx] : 0; }
    bs[tid] = sum; __syncthreads();
    for (int off = 1; off < 1024; off <<= 1) {
        int v = (tid >= off) ? bs[tid - off] : 0;
        __syncthreads();
        bs[tid] += v;
        __syncthreads();
    }
    int run = (tid > 0) ? bs[tid - 1] : 0;
    for (int i = 0; i < CH; i++) {
        int idx = base + i;
        if (idx < N) { rowptr[idx] = run; run += deg[idx]; }
    }
    if (tid == 0) rowptr[N] = bs[1023];
}
__global__ void edge_bucket(const int* __restrict__ ei, int* __restrict__ cursor,
                            int* __restrict__ csrc, int E) {
    int e = blockIdx.x * 256 + threadIdx.x;
    if (e < E) {
        int d = ei[E + e];
        int p = atomicAdd(&cursor[d], 1);
        csrc[p] = ei[e];
    }
}

// one wave per node, bf16 m rows (512B each): agg = sum of in-edge m[src]
__global__ __launch_bounds__(256)
void agg_bf16(const unsigned short* __restrict__ m, const int* __restrict__ rowptr,
              const int* __restrict__ csrc, unsigned short* __restrict__ agg, int N) {
    int wv = (blockIdx.x * 256 + threadIdx.x) >> 6;
    int lane = threadIdx.x & 63;
    if (wv >= N) return;
    int s0 = rowptr[wv], s1 = rowptr[wv + 1];
    float a0 = 0.f, a1 = 0.f, a2 = 0.f, a3 = 0.f;
    for (int e = s0; e < s1; e++) {
        const unsigned short* r = m + (size_t)csrc[e] * HDIM + lane * 4;
        ushort4 v = *(const ushort4*)r;
        a0 += bf2f(v.x); a1 += bf2f(v.y); a2 += bf2f(v.z); a3 += bf2f(v.w);
    }
    ushort4 o = { f2bf(a0), f2bf(a1), f2bf(a2), f2bf(a3) };
    *(ushort4*)(agg + (size_t)wv * HDIM + lane * 4) = o;
}

// -------------------------- attention + head --------------------------------
__global__ void seg_starts(const int* __restrict__ batch, int* __restrict__ starts,
                           int N, int G) {
    int n = blockIdx.x * 256 + threadIdx.x;
    if (n > N) return;
    int b  = (n < N) ? batch[n] : G;
    int bp = (n == 0) ? -1 : batch[n - 1];
    for (int g = bp + 1; g <= b; g++) starts[g] = n;
}

// fused fp32 GEMM scores: 64 rows x 128 cols per block, tanh*w2 + row-reduce.
__global__ __launch_bounds__(256)
void att_scores2(const float* __restrict__ h, const float* __restrict__ w1,
                 const float* __restrict__ b1, const float* __restrict__ w2,
                 const float* __restrict__ b2, float* __restrict__ scores) {
    __shared__ float As[16][68];
    __shared__ float Bs[16][136];
    __shared__ float red[64][17];
    const int tid = threadIdx.x;
    const int row0 = blockIdx.x * 64;
    const int tm = (tid & 15) * 4, tn = (tid >> 4) * 8;
    const int ar = tid >> 2, ac = (tid & 3) * 4;
    const int br = tid >> 4, bc = (tid & 15) * 8;
    float acc[4][8] = {};
    for (int k0 = 0; k0 < HDIM; k0 += 16) {
        float4 av = {0.f, 0.f, 0.f, 0.f};
        int arow = row0 + ar;
        if (arow < N_NODES) av = *(const float4*)(h + (size_t)arow * HDIM + k0 + ac);
        As[ac + 0][ar] = av.x; As[ac + 1][ar] = av.y;
        As[ac + 2][ar] = av.z; As[ac + 3][ar] = av.w;
        *(float4*)&Bs[br][bc]     = *(const float4*)(w1 + (size_t)(k0 + br) * 128 + bc);
        *(float4*)&Bs[br][bc + 4] = *(const float4*)(w1 + (size_t)(k0 + br) * 128 + bc + 4);
        __syncthreads();
        #pragma unroll
        for (int kk = 0; kk < 16; kk++) {
            float4 a4 = *(const float4*)&As[kk][tm];
            float4 b4 = *(const float4*)&Bs[kk][tn];
            float4 c4 = *(const float4*)&Bs[kk][tn + 4];
            float aa[4] = {a4.x, a4.y, a4.z, a4.w};
            float bb[8] = {b4.x, b4.y, b4.z, b4.w, c4.x, c4.y, c4.z, c4.w};
            #pragma unroll
            for (int i = 0; i < 4; i++)
                #pragma unroll
                for (int j = 0; j < 8; j++) acc[i][j] += aa[i] * bb[j];
        }
        __syncthreads();
    }
    #pragma unroll
    for (int i = 0; i < 4; i++) {
        float s = 0.f;
        #pragma unroll
        for (int j = 0; j < 8; j++)
            s += tanhf(acc[i][j] + b1[tn + j]) * w2[tn + j];
        red[tm + i][tid >> 4] = s;
    }
    __syncthreads();
    if (tid < 64) {
        float s = 0.f;
        #pragma unroll
        for (int g = 0; g < 16; g++) s += red[tid][g];
        int n = row0 + tid;
        if (n < N_NODES) scores[n] = s + b2[0];
    }
}

// per-graph max + denom: one wave per graph
__global__ __launch_bounds__(256)
void seg_stats(const float* __restrict__ scores, const int* __restrict__ starts,
               float* __restrict__ gmax, float* __restrict__ gden) {
    int wv = (blockIdx.x * 256 + threadIdx.x) >> 6;
    int lane = threadIdx.x & 63;
    if (wv >= N_GRAPHS) return;
    int s0 = starts[wv], s1 = starts[wv + 1];
    float mx = -1e30f;
    for (int n = s0 + lane; n < s1; n += 64) mx = fmaxf(mx, scores[n]);
    #pragma unroll
    for (int off = 32; off > 0; off >>= 1) mx = fmaxf(mx, __shfl_xor(mx, off));
    float se = 0.f;
    for (int n = s0 + lane; n < s1; n += 64) se += expf(scores[n] - mx);
    #pragma unroll
    for (int off = 32; off > 0; off >>= 1) se += __shfl_xor(se, off);
    if (lane == 0) { gmax[wv] = mx; gden[wv] = se; }
}

__global__ void node_weights(const float* __restrict__ scores, const int* __restrict__ batch,
                             const float* __restrict__ gmax, const float* __restrict__ gden,
                             float* __restrict__ wn) {
    int n = blockIdx.x * 256 + threadIdx.x;
    if (n >= N_NODES) return;
    int g = batch[n];
    float d = gden[g];
    wn[n] = (d > 0.f) ? expf(scores[n] - gmax[g]) / d : 0.f;
}

// deterministic 4-stripe weighted pool: block (g,s) handles nodes n≡s (mod 4)
__global__ __launch_bounds__(256)
void pool_partial(const float* __restrict__ h, const float* __restrict__ wn,
                  const int* __restrict__ starts, float* __restrict__ part) {
    int g = blockIdx.x, s = blockIdx.y, tid = threadIdx.x;
    int s0 = starts[g], s1 = starts[g + 1];
    float acc = 0.f;
    for (int n = s0 + s; n < s1; n += 4)
        acc += wn[n] * h[(size_t)n * HDIM + tid];
    part[((size_t)(g * 4 + s)) * HDIM + tid] = acc;
}
__global__ __launch_bounds__(256)
void pool_reduce(const float* __restrict__ part, float* __restrict__ pooled) {
    int g = blockIdx.x, tid = threadIdx.x;
    float s = 0.f;
    #pragma unroll
    for (int i = 0; i < 4; i++) s += part[((size_t)(g * 4 + i)) * HDIM + tid];
    pooled[g * HDIM + tid] = s;
}

__global__ __launch_bounds__(128)
void classify(const float* __restrict__ pooled, const float* __restrict__ w1,
              const float* __restrict__ b1, const float* __restrict__ w2,
              const float* __restrict__ b2, float* __restrict__ out) {
    int g = blockIdx.x;
    int tid = threadIdx.x;
    float acc = 0.f;
    for (int k = 0; k < HDIM; k++) acc += pooled[g * HDIM + k] * w1[k * 128 + tid];
    float t = fmaxf(acc + b1[tid], 0.f);
    float v = t * w2[tid];
    __shared__ float red[128];
    red[tid] = v; __syncthreads();
    for (int off = 64; off > 0; off >>= 1) {
        if (tid < off) red[tid] += red[tid + off];
        __syncthreads();
    }
    if (tid == 0) out[g] = red[0] + b2[0];
}

// ---------------------------------------------------------------------------
extern "C" void kernel_launch(void* const* d_in, const int* in_sizes, int n_in,
                              void* d_out, int out_size, void* d_ws, size_t ws_size,
                              hipStream_t stream) {
    const float* x      = (const float*)d_in[0];
    const int*   ei     = (const int*)  d_in[1];
    const int*   batch  = (const int*)  d_in[2];
    const float* proj_w = (const float*)d_in[3];
    const float* proj_b = (const float*)d_in[4];
    const float* conv_w = (const float*)d_in[5];
    const float* w_ih   = (const float*)d_in[6];
    const float* w_hh   = (const float*)d_in[7];
    const float* b_ih   = (const float*)d_in[8];
    const float* b_hh   = (const float*)d_in[9];
    const float* att_w1 = (const float*)d_in[10];
    const float* att_b1 = (const float*)d_in[11];
    const float* att_w2 = (const float*)d_in[12];
    const float* att_b2 = (const float*)d_in[13];
    const float* cls_w1 = (const float*)d_in[14];
    const float* cls_b1 = (const float*)d_in[15];
    const float* cls_w2 = (const float*)d_in[16];
    const float* cls_b2 = (const float*)d_in[17];
    float* out = (float*)d_out;

    char* ws = (char*)d_ws;
    size_t off = 0;
    auto alloc = [&](size_t bytes) -> void* {
        void* p = ws + off;
        off = (off + bytes + 255) & ~(size_t)255;
        return p;
    };
    // persistent
    float*          hf0    = (float*)         alloc((size_t)M_PAD * HDIM * 4);
    unsigned short* hb0    = (unsigned short*)alloc((size_t)M_PAD * HDIM * 2);
    unsigned short* hb1    = (unsigned short*)alloc((size_t)M_PAD * HDIM * 2);
    unsigned short* wihb   = (unsigned short*)alloc((size_t)3 * HDIM * HDIM * 2);
    unsigned short* whhb   = (unsigned short*)alloc((size_t)3 * HDIM * HDIM * 2);
    unsigned short* projWT = (unsigned short*)alloc((size_t)HDIM * KP * 2);
    unsigned short* convT  = (unsigned short*)alloc((size_t)L_LAYERS * HDIM * HDIM * 2);
    int*   rowptr = (int*)  alloc((N_NODES + 1) * 4);
    int*   cursor = (int*)  alloc((N_NODES + 1) * 4);
    int*   deg    = (int*)  alloc(N_NODES * 4);
    int*   csrc   = (int*)  alloc(N_EDGES * 4);
    float* scores = (float*)alloc(N_NODES * 4);
    int*   starts = (int*)  alloc((N_GRAPHS + 1) * 4);
    float* gmax   = (float*)alloc(N_GRAPHS * 4);
    float* gden   = (float*)alloc(N_GRAPHS * 4);
    float* wnode  = (float*)alloc(N_NODES * 4);
    float* ppart  = (float*)alloc((size_t)N_GRAPHS * 4 * HDIM * 4);
    float* pooled = (float*)alloc((size_t)N_GRAPHS * HDIM * 4);
    // union region: xb (proj phase) overlaps {mb, aggb, hf1} (layer phase)
    char* U = (char*)alloc((size_t)M_PAD * KP * 2 > (size_t)M_PAD * HDIM * (2 + 2 + 4)
                               ? (size_t)M_PAD * KP * 2
                               : (size_t)M_PAD * HDIM * (2 + 2 + 4));
    unsigned short* xb   = (unsigned short*)U;
    unsigned short* mb   = (unsigned short*)U;
    unsigned short* aggb = (unsigned short*)(U + (size_t)M_PAD * HDIM * 2);
    float*          hf1  = (float*)         (U + (size_t)M_PAD * HDIM * 4);
    (void)ws_size; (void)in_sizes; (void)n_in; (void)out_size;

    // ---- one-time prep ----
    prep_x     <<<dim3((N_NODES * KP) / 256), dim3(256), 0, stream>>>(x, xb);
    prep_projw <<<dim3((HDIM * KP) / 256), dim3(256), 0, stream>>>(proj_w, projWT);
    prep_convw <<<dim3((L_LAYERS * HDIM * HDIM) / 256), dim3(256), 0, stream>>>(conv_w, convT);
    prep_cast2 <<<dim3((3 * HDIM * HDIM) / 256), dim3(256), 0, stream>>>(
        w_ih, w_hh, wihb, whhb, 3 * HDIM * HDIM);

    // ---- input projection (+bias+relu) -> hf0 (f32) + hb0 (bf16) ----
    mm128<1><<<dim3(M_PAD / 128, 2), dim3(256), 0, stream>>>(
        xb, KP, projWT, KP, proj_b, hf0, hb0, KP / 32);

    // ---- CSR by dst ----
    hipMemsetAsync(deg, 0, N_NODES * 4, stream);
    edge_count<<<dim3((N_EDGES + 255) / 256), dim3(256), 0, stream>>>(ei, deg, N_EDGES);
    scan_rowptr<<<dim3(1), dim3(1024), 0, stream>>>(deg, rowptr, N_NODES);
    hipMemcpyAsync(cursor, rowptr, (N_NODES + 1) * 4, hipMemcpyDeviceToDevice, stream);
    edge_bucket<<<dim3((N_EDGES + 255) / 256), dim3(256), 0, stream>>>(ei, cursor, csrc, N_EDGES);
    seg_starts<<<dim3((N_NODES + 256) / 256), dim3(256), 0, stream>>>(batch, starts,
                                                                      N_NODES, N_GRAPHS);

    // ---- 5 message-passing layers ----
    float*          hfc = hf0;  float*          hfn = hf1;
    unsigned short* hbc = hb0;  unsigned short* hbn = hb1;
    for (int l = 0; l < L_LAYERS; l++) {
        mm128<0><<<dim3(M_PAD / 128, 2), dim3(256), 0, stream>>>(
            hbc, HDIM, convT + (size_t)l * HDIM * HDIM, HDIM, nullptr, nullptr, mb, HDIM / 32);
        agg_bf16<<<dim3((N_NODES * 64) / 256), dim3(256), 0, stream>>>(
            mb, rowptr, csrc, aggb, N_NODES);
        gru_mfma<<<dim3(M_PAD / 64, 4), dim3(256), 0, stream>>>(
            aggb, hbc, hfc, wihb, whhb, b_ih, b_hh, hfn, hbn);
        float* tf = hfc; hfc = hfn; hfn = tf;
        unsigned short* tb = hbc; hbc = hbn; hbn = tb;
    }

    // ---- attention pooling + classifier (fp32 on final h) ----
    att_scores2<<<dim3((N_NODES + 63) / 64), dim3(256), 0, stream>>>(
        hfc, att_w1, att_b1, att_w2, att_b2, scores);
    seg_stats<<<dim3((N_GRAPHS * 64 + 255) / 256), dim3(256), 0, stream>>>(
        scores, starts, gmax, gden);
    node_weights<<<dim3((N_NODES + 255) / 256), dim3(256), 0, stream>>>(
        scores, batch, gmax, gden, wnode);
    pool_partial<<<dim3(N_GRAPHS, 4), dim3(256), 0, stream>>>(hfc, wnode, starts, ppart);
    pool_reduce<<<dim3(N_GRAPHS), dim3(256), 0, stream>>>(ppart, pooled);
    classify<<<dim3(N_GRAPHS), dim3(128), 0, stream>>>(pooled, cls_w1, cls_b1,
                                                       cls_w2, cls_b2, out);
}